// Round 1
// baseline (377.917 us; speedup 1.0000x reference)
//
#include <hip/hip_runtime.h>
#include <math.h>

// ---- problem constants (from reference setup_inputs) ----
#define BQ 2
#define LQ 13294
#define LEN_IN 13294
#define D_MODEL 256
#define N_HEADS 8
#define N_LEVELS 4
#define N_POINTS 4
#define D_HEAD 32
#define M_ROWS (BQ * LQ)   // 26588

__device__ __constant__ int c_HW[N_LEVELS]    = {100, 50, 25, 13};
__device__ __constant__ int c_START[N_LEVELS] = {0, 10000, 12500, 13125};

// ---------------------------------------------------------------------------
// fp32 tiled GEMM:  C[M,N] = A[M,K] @ W[K,N] + bias[N]
// 64x64 tile, 256 threads, 4x4 micro-tile per thread, K staged by 16.
// N is always a multiple of 64; M guarded.
// ---------------------------------------------------------------------------
#define TM 64
#define TN 64
#define TK 16

__global__ __launch_bounds__(256) void gemm_bias(
    const float* __restrict__ A, const float* __restrict__ W,
    const float* __restrict__ bias, float* __restrict__ C,
    int M, int N, int K) {
  __shared__ float As[TK][TM + 4];   // transposed A tile, padded
  __shared__ float Bs[TK][TN];

  const int tid = threadIdx.x;
  const int tx = tid & 15;         // 0..15 -> n
  const int ty = tid >> 4;         // 0..15 -> m
  const int m0 = blockIdx.x * TM;
  const int n0 = blockIdx.y * TN;

  float acc[4][4] = {};

  for (int k0 = 0; k0 < K; k0 += TK) {
    // A tile: 64 rows x 16 k. Each thread: one float4 along k.
    {
      const int row = tid >> 2;          // 0..63
      const int kk  = (tid & 3) * 4;     // 0,4,8,12
      const int m = m0 + row;
      float4 a = make_float4(0.f, 0.f, 0.f, 0.f);
      if (m < M) a = *(const float4*)&A[(size_t)m * K + k0 + kk];
      As[kk + 0][row] = a.x;
      As[kk + 1][row] = a.y;
      As[kk + 2][row] = a.z;
      As[kk + 3][row] = a.w;
    }
    // B tile: 16 k x 64 n. Each thread: one float4 along n.
    {
      const int kk = tid >> 4;           // 0..15
      const int nn = (tid & 15) * 4;
      float4 b = *(const float4*)&W[(size_t)(k0 + kk) * N + n0 + nn];
      *(float4*)&Bs[kk][nn] = b;
    }
    __syncthreads();

#pragma unroll
    for (int kk = 0; kk < TK; ++kk) {
      float a[4], b[4];
#pragma unroll
      for (int i = 0; i < 4; ++i) a[i] = As[kk][ty * 4 + i];
#pragma unroll
      for (int j = 0; j < 4; ++j) b[j] = Bs[kk][tx * 4 + j];
#pragma unroll
      for (int i = 0; i < 4; ++i)
#pragma unroll
        for (int j = 0; j < 4; ++j) acc[i][j] += a[i] * b[j];
    }
    __syncthreads();
  }

#pragma unroll
  for (int i = 0; i < 4; ++i) {
    const int m = m0 + ty * 4 + i;
    if (m >= M) continue;
#pragma unroll
    for (int j = 0; j < 4; ++j) {
      const int n = n0 + tx * 4 + j;
      C[(size_t)m * N + n] = acc[i][j] + bias[n];
    }
  }
}

// ---------------------------------------------------------------------------
// Deformable sampling. One block (256 threads) per query row (b*LQ + q).
// Phase 1: softmax of 128 attention logits (16 per head).
// Phase 2: 128 threads compute the 4 bilinear taps for their (h,l,p) point:
//          combined weight (bilinear * valid * aw) and value-row index.
// Phase 3: thread (h,d) accumulates 16 points x 4 taps from value and writes
//          mid[b,q,h,d]. Value reads are 32 consecutive floats per (h,tap)
//          -> coalesced 128B segments.
// ---------------------------------------------------------------------------
__global__ __launch_bounds__(256) void sample_kernel(
    const float* __restrict__ refp,    // (B,LQ,4,2)
    const float* __restrict__ off,     // (B*LQ,256) h*32 + l*8 + p*2 + c
    const float* __restrict__ aw,      // (B*LQ,128) h*16 + l*4 + p
    const float* __restrict__ value,   // (B*LEN_IN,256) h*32 + d
    float* __restrict__ mid) {         // (B*LQ,256)
  const int q = blockIdx.x;            // 0 .. M_ROWS-1
  const int b = q / LQ;
  const int tid = threadIdx.x;

  __shared__ float s_aw[128];
  __shared__ float s_w[128][4];
  __shared__ int   s_idx[128][4];

  if (tid < 128) s_aw[tid] = aw[(size_t)q * 128 + tid];
  __syncthreads();

  if (tid < 8) {  // per-head softmax over 16 logits
    float mx = -1e30f;
#pragma unroll
    for (int i = 0; i < 16; ++i) mx = fmaxf(mx, s_aw[tid * 16 + i]);
    float e[16], sum = 0.f;
#pragma unroll
    for (int i = 0; i < 16; ++i) {
      e[i] = expf(s_aw[tid * 16 + i] - mx);
      sum += e[i];
    }
    const float inv = 1.0f / sum;
#pragma unroll
    for (int i = 0; i < 16; ++i) s_aw[tid * 16 + i] = e[i] * inv;
  }
  __syncthreads();

  if (tid < 128) {
    const int h = tid >> 4;
    const int lp = tid & 15;
    const int l = lp >> 2;
    const int p = lp & 3;
    const int HW = c_HW[l];           // square levels: H == W
    const float fW = (float)HW;

    const float rx = refp[((size_t)q * 4 + l) * 2 + 0];
    const float ry = refp[((size_t)q * 4 + l) * 2 + 1];
    const float ox = off[(size_t)q * 256 + h * 32 + l * 8 + p * 2 + 0];
    const float oy = off[(size_t)q * 256 + h * 32 + l * 8 + p * 2 + 1];

    // match reference: loc = ref + off/normalizer ; x = loc*W - 0.5
    const float x = (rx + ox / fW) * fW - 0.5f;
    const float y = (ry + oy / fW) * fW - 0.5f;
    const float x0 = floorf(x);
    const float y0 = floorf(y);
    const float a = s_aw[tid];

#pragma unroll
    for (int t = 0; t < 4; ++t) {
      const int dx = t & 1;
      const int dy = t >> 1;
      const float xi = x0 + (float)dx;
      const float yi = y0 + (float)dy;
      const float wgt = (1.0f - fabsf(x - xi)) * (1.0f - fabsf(y - yi));
      const bool valid =
          (xi >= 0.f) && (xi <= fW - 1.f) && (yi >= 0.f) && (yi <= fW - 1.f);
      int xc = (int)xi; xc = xc < 0 ? 0 : (xc > HW - 1 ? HW - 1 : xc);
      int yc = (int)yi; yc = yc < 0 ? 0 : (yc > HW - 1 ? HW - 1 : yc);
      s_w[tid][t] = valid ? wgt * a : 0.f;
      s_idx[tid][t] = c_START[l] + yc * HW + xc;
    }
  }
  __syncthreads();

  const int h = tid >> 5;
  const int d = tid & 31;
  float acc = 0.f;
  const float* vb = value + (size_t)b * LEN_IN * 256 + h * 32 + d;
#pragma unroll 4
  for (int lp = 0; lp < 16; ++lp) {
    const int si = h * 16 + lp;
#pragma unroll
    for (int t = 0; t < 4; ++t) {
      const float w = s_w[si][t];
      const int row = s_idx[si][t];
      acc += w * vb[(size_t)row * 256];
    }
  }
  mid[(size_t)q * 256 + tid] = acc;
}

// ---------------------------------------------------------------------------
extern "C" void kernel_launch(void* const* d_in, const int* in_sizes, int n_in,
                              void* d_out, int out_size, void* d_ws,
                              size_t ws_size, hipStream_t stream) {
  const float* query  = (const float*)d_in[0];
  const float* refp   = (const float*)d_in[1];
  const float* inpf   = (const float*)d_in[2];
  // d_in[3] spatial shapes, d_in[4] level starts: compile-time constants.
  const float* W_off  = (const float*)d_in[5];
  const float* b_off  = (const float*)d_in[6];
  const float* W_attn = (const float*)d_in[7];
  const float* b_attn = (const float*)d_in[8];
  const float* W_val  = (const float*)d_in[9];
  const float* b_val  = (const float*)d_in[10];
  const float* W_out  = (const float*)d_in[11];
  const float* b_out  = (const float*)d_in[12];
  float* out = (float*)d_out;

  float* ws = (float*)d_ws;
  float* v_buf   = ws;                               // M*256
  float* off_buf = v_buf + (size_t)M_ROWS * 256;     // M*256
  float* aw_buf  = off_buf + (size_t)M_ROWS * 256;   // M*128
  float* mid_buf = aw_buf + (size_t)M_ROWS * 128;    // M*256

  const dim3 blk(256);
  const int mg = (M_ROWS + TM - 1) / TM;

  // value = input_flatten @ W_val + b_val
  gemm_bias<<<dim3(mg, 256 / TN), blk, 0, stream>>>(inpf, W_val, b_val, v_buf,
                                                    M_ROWS, 256, 256);
  // off = query @ W_off + b_off
  gemm_bias<<<dim3(mg, 256 / TN), blk, 0, stream>>>(query, W_off, b_off,
                                                    off_buf, M_ROWS, 256, 256);
  // aw logits = query @ W_attn + b_attn
  gemm_bias<<<dim3(mg, 128 / TN), blk, 0, stream>>>(query, W_attn, b_attn,
                                                    aw_buf, M_ROWS, 128, 256);
  // softmax + deformable bilinear sampling -> mid
  sample_kernel<<<dim3(M_ROWS), blk, 0, stream>>>(refp, off_buf, aw_buf, v_buf,
                                                  mid_buf);
  // out = mid @ W_out + b_out
  gemm_bias<<<dim3(mg, 256 / TN), blk, 0, stream>>>(mid_buf, W_out, b_out, out,
                                                    M_ROWS, 256, 256);
}

// Round 2
// 235.676 us; speedup vs baseline: 1.6035x; 1.6035x over previous
//
#include <hip/hip_runtime.h>
#include <math.h>

// ---- problem constants ----
#define BQ 2
#define LQ 13294
#define LEN_IN 13294
#define D_MODEL 256
#define N_HEADS 8
#define N_LEVELS 4
#define N_POINTS 4
#define D_HEAD 32
#define M_ROWS (BQ * LQ)   // 26588

__device__ __constant__ int c_HW[N_LEVELS]    = {100, 50, 25, 13};
__device__ __constant__ int c_START[N_LEVELS] = {0, 10000, 12500, 13125};

typedef __attribute__((ext_vector_type(8))) short bf16x8;
typedef __attribute__((ext_vector_type(4))) float f32x4;

__device__ inline unsigned short f2bf(float f) {
  union { float f; unsigned int u; } x; x.f = f;
  unsigned int u = x.u;
  unsigned int r = (u + 0x7fffu + ((u >> 16) & 1u)) >> 16;
  return (unsigned short)r;
}
__device__ inline float bf2f(unsigned short b) {
  union { unsigned int u; float f; } x; x.u = ((unsigned int)b) << 16;
  return x.f;
}

// ---------------------------------------------------------------------------
// Weight prep: transpose+convert W (fp32 [K][N]) -> Wt (bf16 [N][K]).
// Also builds the fused off|attn weight (384 x 256) and bias (384).
// ---------------------------------------------------------------------------
__global__ __launch_bounds__(256) void prep_weights(
    const float* __restrict__ W_off, const float* __restrict__ b_off,
    const float* __restrict__ W_attn, const float* __restrict__ b_attn,
    const float* __restrict__ W_val, const float* __restrict__ W_out,
    unsigned short* __restrict__ Wval_t, unsigned short* __restrict__ Woa_t,
    unsigned short* __restrict__ Wout_t, float* __restrict__ b_oa) {
  const int idx = blockIdx.x * 256 + threadIdx.x;
  const int SZ1 = 256 * 256;           // val
  const int SZ2 = 384 * 256;           // oa
  if (idx < SZ1) {
    const int n = idx >> 8, k = idx & 255;
    Wval_t[idx] = f2bf(W_val[k * 256 + n]);
  } else if (idx < SZ1 + SZ2) {
    const int j = idx - SZ1;
    const int n = j >> 8, k = j & 255;
    const float v = (n < 256) ? W_off[k * 256 + n] : W_attn[k * 128 + (n - 256)];
    Woa_t[j] = f2bf(v);
  } else if (idx < SZ1 + SZ2 + SZ1) {
    const int j = idx - SZ1 - SZ2;
    const int n = j >> 8, k = j & 255;
    Wout_t[j] = f2bf(W_out[k * 256 + n]);
  }
  if (blockIdx.x == 0) b_oa[threadIdx.x] = b_off[threadIdx.x];
  if (blockIdx.x == 1 && threadIdx.x < 128)
    b_oa[256 + threadIdx.x] = b_attn[threadIdx.x];
}

// ---------------------------------------------------------------------------
// bf16 MFMA GEMM: C[M,N] = A[M,K] @ Wt^T + bias  (Wt is [N][K] bf16)
// 128x128 tile, BK=32, 4 waves (2x2 of 64x64), mfma_f32_16x16x32_bf16.
// A is fp32 (converted in staging) or bf16. C is fp32 or bf16.
// ---------------------------------------------------------------------------
#define BM 128
#define BN 128
#define BK 32
#define LDK 40   // +8 bf16 pad (16B) to spread frag-read banks

template <bool A_BF16, bool C_BF16>
__global__ __launch_bounds__(256) void gemm_mfma(
    const void* __restrict__ Ap, const unsigned short* __restrict__ Wt,
    const float* __restrict__ bias, void* __restrict__ Cp,
    int M, int N, int K) {
  __shared__ unsigned short As[BM * LDK];
  __shared__ unsigned short Bs[BN * LDK];
  const int tid = threadIdx.x;
  const int m0 = blockIdx.x * BM;
  const int n0 = blockIdx.y * BN;
  const int wave = tid >> 6;
  const int lane = tid & 63;
  const int wm = (wave & 1) * 64;
  const int wn = (wave >> 1) * 64;
  const int fr = lane & 15;
  const int fq = lane >> 4;

  f32x4 acc[4][4];
#pragma unroll
  for (int i = 0; i < 4; ++i)
#pragma unroll
    for (int j = 0; j < 4; ++j) acc[i][j] = (f32x4){0.f, 0.f, 0.f, 0.f};

  for (int k0 = 0; k0 < K; k0 += BK) {
    // ---- stage A tile (BM x BK) ----
    if (A_BF16) {
      const int m = tid >> 2;
      const int ch = tid & 3;   // 16B chunk along k
#pragma unroll
      for (int half = 0; half < 2; ++half) {
        const int mm = m + half * 64;
        const int gm = m0 + mm;
        uint4 v = make_uint4(0u, 0u, 0u, 0u);
        if (gm < M)
          v = *(const uint4*)((const unsigned short*)Ap + (size_t)gm * K + k0 + ch * 8);
        *(uint4*)&As[mm * LDK + ch * 8] = v;
      }
    } else {
      const int m = tid >> 3;
      const int kq = tid & 7;   // float4 index along k
#pragma unroll
      for (int qtr = 0; qtr < 4; ++qtr) {
        const int mm = m + qtr * 32;
        const int gm = m0 + mm;
        float4 v = make_float4(0.f, 0.f, 0.f, 0.f);
        if (gm < M)
          v = *(const float4*)((const float*)Ap + (size_t)gm * K + k0 + kq * 4);
        ushort4 h;
        h.x = f2bf(v.x); h.y = f2bf(v.y); h.z = f2bf(v.z); h.w = f2bf(v.w);
        *(ushort4*)&As[mm * LDK + kq * 4] = h;
      }
    }
    // ---- stage B tile (BN x BK) from Wt [n][k] ----
    {
      const int n = tid >> 2;
      const int ch = tid & 3;
#pragma unroll
      for (int half = 0; half < 2; ++half) {
        const int nn = n + half * 64;
        uint4 v = *(const uint4*)(Wt + (size_t)(n0 + nn) * K + k0 + ch * 8);
        *(uint4*)&Bs[nn * LDK + ch * 8] = v;
      }
    }
    __syncthreads();

    bf16x8 af[4], bfr[4];
#pragma unroll
    for (int i = 0; i < 4; ++i)
      af[i] = *(const bf16x8*)&As[(wm + i * 16 + fr) * LDK + fq * 8];
#pragma unroll
    for (int j = 0; j < 4; ++j)
      bfr[j] = *(const bf16x8*)&Bs[(wn + j * 16 + fr) * LDK + fq * 8];
#pragma unroll
    for (int i = 0; i < 4; ++i)
#pragma unroll
      for (int j = 0; j < 4; ++j)
        acc[i][j] = __builtin_amdgcn_mfma_f32_16x16x32_bf16(af[i], bfr[j],
                                                            acc[i][j], 0, 0, 0);
    __syncthreads();
  }

  // ---- epilogue: C/D layout col=lane&15, row=(lane>>4)*4+reg ----
  const int col = fr;
  const int row0 = fq * 4;
#pragma unroll
  for (int i = 0; i < 4; ++i) {
#pragma unroll
    for (int j = 0; j < 4; ++j) {
      const int gn = n0 + wn + j * 16 + col;
      const float bb = bias[gn];
#pragma unroll
      for (int r = 0; r < 4; ++r) {
        const int gm = m0 + wm + i * 16 + row0 + r;
        if (gm < M) {
          const float v = acc[i][j][r] + bb;
          if (C_BF16)
            ((unsigned short*)Cp)[(size_t)gm * N + gn] = f2bf(v);
          else
            ((float*)Cp)[(size_t)gm * N + gn] = v;
        }
      }
    }
  }
}

// ---------------------------------------------------------------------------
// Sampler: 2 queries per block, 256 threads.
// Phase A (all threads): softmax via 16-lane shuffles + tap weight/byte-offset
//   precompute, packed into LDS float2 {w, byteoff}.
// Phase B: 128 threads/query, each owns (head, d-pair); 16 pts x 4 taps,
//   one ds_read_b64 + one u32 (bf16x2) global load per tap.
// ---------------------------------------------------------------------------
__global__ __launch_bounds__(256) void sample_kernel(
    const float* __restrict__ refp,          // (B,LQ,4,2) fp32
    const float* __restrict__ oa,            // (M,384) fp32: off(256)|logits(128)
    const unsigned short* __restrict__ value,// (M,256) bf16
    unsigned int* __restrict__ mid) {        // (M,128) u32 = bf16 pairs
  const int tid = threadIdx.x;
  const int qi = tid >> 7;                   // 0/1
  const int q = blockIdx.x * 2 + qi;
  const int b = (q >= LQ) ? 1 : 0;

  __shared__ float2 s_wo[2][4][136];         // [qi][tap][pid + (pid>>4)]

  // ---- Phase A ----
  {
    const int pid = tid & 127;               // h*16 + l*4 + p
    const int h = pid >> 4;
    const int lp = pid & 15;
    const int l = lp >> 2;
    const int p = lp & 3;
    const int HW = c_HW[l];
    const float fW = (float)HW;

    const float logit = oa[(size_t)q * 384 + 256 + pid];
    float mx = logit;
#pragma unroll
    for (int s = 1; s < 16; s <<= 1) mx = fmaxf(mx, __shfl_xor(mx, s, 16));
    float e = expf(logit - mx);
    float sum = e;
#pragma unroll
    for (int s = 1; s < 16; s <<= 1) sum += __shfl_xor(sum, s, 16);
    const float a = e / sum;

    const float2 o = *(const float2*)&oa[(size_t)q * 384 + h * 32 + l * 8 + p * 2];
    const float rx = refp[((size_t)q * 4 + l) * 2 + 0];
    const float ry = refp[((size_t)q * 4 + l) * 2 + 1];
    const float x = (rx + o.x / fW) * fW - 0.5f;
    const float y = (ry + o.y / fW) * fW - 0.5f;
    const float x0 = floorf(x);
    const float y0 = floorf(y);

#pragma unroll
    for (int t = 0; t < 4; ++t) {
      const int dx = t & 1;
      const int dy = t >> 1;
      const float xi = x0 + (float)dx;
      const float yi = y0 + (float)dy;
      const float wgt = (1.0f - fabsf(x - xi)) * (1.0f - fabsf(y - yi));
      const bool valid =
          (xi >= 0.f) && (xi <= fW - 1.f) && (yi >= 0.f) && (yi <= fW - 1.f);
      int xc = (int)xi; xc = xc < 0 ? 0 : (xc > HW - 1 ? HW - 1 : xc);
      int yc = (int)yi; yc = yc < 0 ? 0 : (yc > HW - 1 ? HW - 1 : yc);
      const int row = b * LEN_IN + c_START[l] + yc * HW + xc;
      const int byteoff = row * 512 + h * 64;   // bf16 row = 512B, +h*32 elems
      float2 wo;
      wo.x = valid ? wgt * a : 0.f;
      wo.y = __int_as_float(byteoff);
      s_wo[qi][t][pid + h] = wo;
    }
  }
  __syncthreads();

  // ---- Phase B ----
  {
    const int g = tid & 127;
    const int h = g >> 4;
    const int dp = g & 15;                   // d-pair: d = 2*dp
    const char* vbase = (const char*)value + dp * 4;
    float acc0 = 0.f, acc1 = 0.f;
#pragma unroll 4
    for (int lp = 0; lp < 16; ++lp) {
      const int si = h * 16 + lp + h;        // padded index
#pragma unroll
      for (int t = 0; t < 4; ++t) {
        const float2 f = s_wo[qi][t][si];
        const int off = __float_as_int(f.y);
        const unsigned int v = *(const unsigned int*)(vbase + off);
        acc0 += f.x * __uint_as_float(v << 16);
        acc1 += f.x * __uint_as_float(v & 0xffff0000u);
      }
    }
    const unsigned int packed =
        (unsigned int)f2bf(acc0) | ((unsigned int)f2bf(acc1) << 16);
    mid[(size_t)q * 128 + h * 16 + dp] = packed;
  }
}

// ---------------------------------------------------------------------------
extern "C" void kernel_launch(void* const* d_in, const int* in_sizes, int n_in,
                              void* d_out, int out_size, void* d_ws,
                              size_t ws_size, hipStream_t stream) {
  const float* query  = (const float*)d_in[0];
  const float* refp   = (const float*)d_in[1];
  const float* inpf   = (const float*)d_in[2];
  const float* W_off  = (const float*)d_in[5];
  const float* b_off  = (const float*)d_in[6];
  const float* W_attn = (const float*)d_in[7];
  const float* b_attn = (const float*)d_in[8];
  const float* W_val  = (const float*)d_in[9];
  const float* b_val  = (const float*)d_in[10];
  const float* W_out  = (const float*)d_in[11];
  const float* b_out  = (const float*)d_in[12];
  float* out = (float*)d_out;

  unsigned char* w = (unsigned char*)d_ws;
  unsigned short* Wval_t = (unsigned short*)w;            w += 256 * 256 * 2;
  unsigned short* Woa_t  = (unsigned short*)w;            w += 384 * 256 * 2;
  unsigned short* Wout_t = (unsigned short*)w;            w += 256 * 256 * 2;
  float*          b_oa   = (float*)w;                     w += 384 * 4 + 64;
  unsigned short* v_buf  = (unsigned short*)w;            w += (size_t)M_ROWS * 256 * 2;
  float*          oa_buf = (float*)w;                     w += (size_t)M_ROWS * 384 * 4;
  unsigned int*   mid_buf = (unsigned int*)w;             // M*128 u32

  const dim3 blk(256);
  const int mg = (M_ROWS + BM - 1) / BM;   // 208

  prep_weights<<<dim3(896), blk, 0, stream>>>(W_off, b_off, W_attn, b_attn,
                                              W_val, W_out, Wval_t, Woa_t,
                                              Wout_t, b_oa);
  // value = input_flatten @ W_val + b_val   -> bf16
  gemm_mfma<false, true><<<dim3(mg, 2), blk, 0, stream>>>(
      inpf, Wval_t, b_val, v_buf, M_ROWS, 256, 256);
  // off|logits = query @ [W_off|W_attn] + [b_off|b_attn] -> fp32
  gemm_mfma<false, false><<<dim3(mg, 3), blk, 0, stream>>>(
      query, Woa_t, b_oa, oa_buf, M_ROWS, 384, 256);
  // softmax + bilinear sampling -> mid (bf16)
  sample_kernel<<<dim3(M_ROWS / 2), blk, 0, stream>>>(refp, oa_buf, v_buf,
                                                      mid_buf);
  // out = mid @ W_out + b_out -> fp32
  gemm_mfma<true, false><<<dim3(mg, 2), blk, 0, stream>>>(
      mid_buf, Wout_t, b_out, out, M_ROWS, 256, 256);
}

// Round 3
// 223.838 us; speedup vs baseline: 1.6884x; 1.0529x over previous
//
#include <hip/hip_runtime.h>
#include <math.h>

// ---- problem constants ----
#define BQ 2
#define LQ 13294
#define LEN_IN 13294
#define M_ROWS 26588          // BQ*LQ

__device__ __constant__ int c_HW[4]    = {100, 50, 25, 13};
__device__ __constant__ int c_START[4] = {0, 10000, 12500, 13125};

typedef __attribute__((ext_vector_type(8))) short bf16x8;
typedef __attribute__((ext_vector_type(4))) float f32x4;
typedef __attribute__((ext_vector_type(2))) float f32x2;

__device__ inline unsigned short f2bf(float f) {
  union { float f; unsigned int u; } x; x.f = f;
  unsigned int u = x.u;
  return (unsigned short)((u + 0x7fffu + ((u >> 16) & 1u)) >> 16);
}
__device__ inline float h2f(unsigned short h) {
  _Float16 x; __builtin_memcpy(&x, &h, 2); return (float)x;
}
__device__ inline unsigned short f2h(float f) {
  _Float16 x = (_Float16)f; unsigned short u; __builtin_memcpy(&u, &x, 2); return u;
}

__device__ inline void gl_lds16(const void* g, void* l) {
  __builtin_amdgcn_global_load_lds(
      (const __attribute__((address_space(1))) unsigned int*)g,
      (__attribute__((address_space(3))) unsigned int*)l, 16, 0, 0);
}

// ---------------------------------------------------------------------------
// Fused prep: (a) fp32->bf16 conversion of query & input_flatten (grid-stride
// float4 chunks, blocks [0, CONV_BLKS)); (b) weight transpose+convert to
// bf16 [N][K] (blocks [CONV_BLKS, CONV_BLKS+896)); (c) fused oa bias.
// ---------------------------------------------------------------------------
#define CONV_BLKS 3456
#define N4EACH (M_ROWS * 64)   // float4s per matrix (M*256/4)

__global__ __launch_bounds__(256) void prep_all(
    const float* __restrict__ query, const float* __restrict__ inpf,
    const float* __restrict__ W_off, const float* __restrict__ b_off,
    const float* __restrict__ W_attn, const float* __restrict__ b_attn,
    const float* __restrict__ W_val, const float* __restrict__ W_out,
    unsigned short* __restrict__ q_bf, unsigned short* __restrict__ in_bf,
    unsigned short* __restrict__ Wval_t, unsigned short* __restrict__ Woa_t,
    unsigned short* __restrict__ Wout_t, float* __restrict__ b_oa) {
  const int bx = blockIdx.x;
  if (bx < CONV_BLKS) {
    int i = bx * 256 + threadIdx.x;
    const int stride = CONV_BLKS * 256;
    for (; i < 2 * N4EACH; i += stride) {
      const float* src; unsigned short* dst; int j;
      if (i < N4EACH) { src = query; dst = q_bf; j = i; }
      else            { src = inpf;  dst = in_bf; j = i - N4EACH; }
      const float4 v = ((const float4*)src)[j];
      ushort4 h;
      h.x = f2bf(v.x); h.y = f2bf(v.y); h.z = f2bf(v.z); h.w = f2bf(v.w);
      ((ushort4*)dst)[j] = h;
    }
    return;
  }
  const int idx = (bx - CONV_BLKS) * 256 + threadIdx.x;
  const int SZ1 = 256 * 256;
  const int SZ2 = 384 * 256;
  if (idx < SZ1) {
    const int n = idx >> 8, k = idx & 255;
    Wval_t[idx] = f2bf(W_val[k * 256 + n]);
  } else if (idx < SZ1 + SZ2) {
    const int j = idx - SZ1;
    const int n = j >> 8, k = j & 255;
    const float v = (n < 256) ? W_off[k * 256 + n] : W_attn[k * 128 + (n - 256)];
    Woa_t[j] = f2bf(v);
  } else {
    const int j = idx - SZ1 - SZ2;
    const int n = j >> 8, k = j & 255;
    Wout_t[j] = f2bf(W_out[k * 256 + n]);
  }
  if (bx == CONV_BLKS) b_oa[threadIdx.x] = b_off[threadIdx.x];
  if (bx == CONV_BLKS + 1 && threadIdx.x < 128)
    b_oa[256 + threadIdx.x] = b_attn[threadIdx.x];
}

// ---------------------------------------------------------------------------
// m97-style bf16 MFMA GEMM: C[M,N] = A[M,256] @ Wt^T + bias, Wt=[N][256] bf16.
// 128x128 tile, BK=64, global_load_lds dwordx4 staging into XOR-swizzled LDS
// (chunk c of row stored at physical chunk c^(row&7) -> 16B-contiguous lanes
// for the DMA, 2-way-only bank aliasing for ds_read_b128 fragment reads).
// CT: 0 = fp32 C, 1 = bf16 C, 2 = fp16 C.
// ---------------------------------------------------------------------------
template <int CT>
__global__ __launch_bounds__(256) void gemm_mfma(
    const unsigned short* __restrict__ A, const unsigned short* __restrict__ Wt,
    const float* __restrict__ bias, void* __restrict__ Cp, int M, int N) {
  __shared__ unsigned short As[128 * 64];   // 16 KB, row = 64 elems (128 B)
  __shared__ unsigned short Bs[128 * 64];
  const int tid = threadIdx.x;
  const int wv = tid >> 6;
  const int lane = tid & 63;
  const int m0 = blockIdx.x * 128;
  const int n0 = blockIdx.y * 128;
  const int wm = (wv & 1) * 64;
  const int wn = (wv >> 1) * 64;
  const int fr = lane & 15;
  const int fq = lane >> 4;
  const int lr = lane >> 3;              // row-within-8 for staging
  const int gch = (lane & 7) ^ lr;       // global chunk this lane fetches

  // per-lane global pointers for the 4 A / 4 B staging instructions
  const unsigned short* ga[4];
  const unsigned short* gb[4];
#pragma unroll
  for (int t = 0; t < 4; ++t) {
    int ar = m0 + wv * 32 + t * 8 + lr;
    if (ar > M - 1) ar = M - 1;          // clamp: dup row, epilogue-guarded
    ga[t] = A + (size_t)ar * 256 + gch * 8;
    gb[t] = Wt + (size_t)(n0 + wv * 32 + t * 8 + lr) * 256 + gch * 8;
  }

  f32x4 acc[4][4];
#pragma unroll
  for (int i = 0; i < 4; ++i)
#pragma unroll
    for (int j = 0; j < 4; ++j) acc[i][j] = (f32x4){0.f, 0.f, 0.f, 0.f};

  for (int k0 = 0; k0 < 256; k0 += 64) {
    __syncthreads();
#pragma unroll
    for (int t = 0; t < 4; ++t) {
      gl_lds16(ga[t], &As[(wv * 32 + t * 8) * 64]);
      gl_lds16(gb[t], &Bs[(wv * 32 + t * 8) * 64]);
      ga[t] += 64; gb[t] += 64;
    }
    __syncthreads();
#pragma unroll
    for (int kk = 0; kk < 2; ++kk) {
      bf16x8 af[4], bf[4];
#pragma unroll
      for (int i = 0; i < 4; ++i) {
        const int row = wm + i * 16 + fr;
        af[i] = *(const bf16x8*)&As[row * 64 + ((kk * 4 + fq) ^ (row & 7)) * 8];
      }
#pragma unroll
      for (int j = 0; j < 4; ++j) {
        const int row = wn + j * 16 + fr;
        bf[j] = *(const bf16x8*)&Bs[row * 64 + ((kk * 4 + fq) ^ (row & 7)) * 8];
      }
#pragma unroll
      for (int i = 0; i < 4; ++i)
#pragma unroll
        for (int j = 0; j < 4; ++j)
          acc[i][j] = __builtin_amdgcn_mfma_f32_16x16x32_bf16(af[i], bf[j],
                                                              acc[i][j], 0, 0, 0);
    }
  }

  // epilogue: C/D layout col=lane&15, row=(lane>>4)*4+reg
  const int col = fr;
  const int row0 = fq * 4;
#pragma unroll
  for (int i = 0; i < 4; ++i) {
#pragma unroll
    for (int j = 0; j < 4; ++j) {
      const int gn = n0 + wn + j * 16 + col;
      const float bb = bias[gn];
#pragma unroll
      for (int r = 0; r < 4; ++r) {
        const int gm = m0 + wm + i * 16 + row0 + r;
        if (gm < M) {
          const float v = acc[i][j][r] + bb;
          if (CT == 1)
            ((unsigned short*)Cp)[(size_t)gm * N + gn] = f2bf(v);
          else if (CT == 2)
            ((unsigned short*)Cp)[(size_t)gm * N + gn] = f2h(v);
          else
            ((float*)Cp)[(size_t)gm * N + gn] = v;
        }
      }
    }
  }
}

// ---------------------------------------------------------------------------
// Sampler: 4 queries/block, 256 threads.
// Phase A (2 passes, 128 thr/query): softmax via 16-lane shuffles + tap
//   {weight, byte-offset} precompute into LDS (fp16 oa input).
// Phase B: 64 thr/query, thread owns (head, 4 d's): 16 pts x 4 taps, each tap
//   one ds_read_b64 + one global uint2 (4 bf16) + packed f32x2 FMAs.
// ---------------------------------------------------------------------------
__global__ __launch_bounds__(256) void sample_kernel(
    const float* __restrict__ refp,           // (B,LQ,4,2) fp32
    const unsigned short* __restrict__ oa,    // (M,384) fp16: off|logits
    const unsigned short* __restrict__ value, // (M,256) bf16
    unsigned int* __restrict__ mid) {         // (M,128) u32 bf16-pairs
  const int tid = threadIdx.x;
  const int q0 = blockIdx.x * 4;

  __shared__ float2 s_wo[4][4][136];          // [qi][tap][h*17+lp]

  // ---- Phase A ----
  {
    const int pid = tid & 127;                // h*16 + l*4 + p
    const int h = pid >> 4;
    const int lp = pid & 15;
    const int l = lp >> 2;
    const int p = lp & 3;
    const int HW = c_HW[l];
    const float fW = (float)HW;
    const int sub = tid >> 7;
#pragma unroll
    for (int qq = 0; qq < 2; ++qq) {
      const int qi = sub * 2 + qq;
      const int q = q0 + qi;
      const int b = (q >= LQ) ? 1 : 0;

      const float logit = h2f(oa[(size_t)q * 384 + 256 + pid]);
      float mx = logit;
#pragma unroll
      for (int s = 1; s < 16; s <<= 1) mx = fmaxf(mx, __shfl_xor(mx, s, 16));
      const float e = expf(logit - mx);
      float sum = e;
#pragma unroll
      for (int s = 1; s < 16; s <<= 1) sum += __shfl_xor(sum, s, 16);
      const float a = e / sum;

      const unsigned int opk =
          *(const unsigned int*)&oa[(size_t)q * 384 + h * 32 + l * 8 + p * 2];
      const float ox = h2f((unsigned short)(opk & 0xffffu));
      const float oy = h2f((unsigned short)(opk >> 16));
      const float rx = refp[((size_t)q * 4 + l) * 2 + 0];
      const float ry = refp[((size_t)q * 4 + l) * 2 + 1];
      const float x = (rx + ox / fW) * fW - 0.5f;
      const float y = (ry + oy / fW) * fW - 0.5f;
      const float x0 = floorf(x);
      const float y0 = floorf(y);

#pragma unroll
      for (int t = 0; t < 4; ++t) {
        const int dx = t & 1;
        const int dy = t >> 1;
        const float xi = x0 + (float)dx;
        const float yi = y0 + (float)dy;
        const float wgt = (1.0f - fabsf(x - xi)) * (1.0f - fabsf(y - yi));
        const bool valid =
            (xi >= 0.f) && (xi <= fW - 1.f) && (yi >= 0.f) && (yi <= fW - 1.f);
        int xc = (int)xi; xc = xc < 0 ? 0 : (xc > HW - 1 ? HW - 1 : xc);
        int yc = (int)yi; yc = yc < 0 ? 0 : (yc > HW - 1 ? HW - 1 : yc);
        const int row = b * LEN_IN + c_START[l] + yc * HW + xc;
        float2 wo;
        wo.x = valid ? wgt * a : 0.f;
        wo.y = __int_as_float(row * 512 + h * 64);  // bf16 row = 512 B
        s_wo[qi][t][h * 17 + lp] = wo;
      }
    }
  }
  __syncthreads();

  // ---- Phase B ----
  {
    const int qi = tid >> 6;
    const int g = tid & 63;
    const int h = g >> 3;
    const int dp8 = g & 7;                    // 8B chunk: 4 bf16 d's
    const int q = q0 + qi;
    const char* vbase = (const char*)value + dp8 * 8;
    f32x2 acc0 = {0.f, 0.f}, acc1 = {0.f, 0.f};
#pragma unroll 4
    for (int lp = 0; lp < 16; ++lp) {
      const int si = h * 17 + lp;
#pragma unroll
      for (int t = 0; t < 4; ++t) {
        const float2 f = s_wo[qi][t][si];
        const uint2 v = *(const uint2*)(vbase + __float_as_int(f.y));
        f32x2 av0 = {__uint_as_float(v.x << 16),
                     __uint_as_float(v.x & 0xffff0000u)};
        f32x2 av1 = {__uint_as_float(v.y << 16),
                     __uint_as_float(v.y & 0xffff0000u)};
        acc0 += f.x * av0;
        acc1 += f.x * av1;
      }
    }
    uint2 pk;
    pk.x = (unsigned int)f2bf(acc0.x) | ((unsigned int)f2bf(acc0.y) << 16);
    pk.y = (unsigned int)f2bf(acc1.x) | ((unsigned int)f2bf(acc1.y) << 16);
    *(uint2*)&mid[(size_t)q * 128 + h * 16 + dp8 * 2] = pk;
  }
}

// ---------------------------------------------------------------------------
extern "C" void kernel_launch(void* const* d_in, const int* in_sizes, int n_in,
                              void* d_out, int out_size, void* d_ws,
                              size_t ws_size, hipStream_t stream) {
  const float* query  = (const float*)d_in[0];
  const float* refp   = (const float*)d_in[1];
  const float* inpf   = (const float*)d_in[2];
  const float* W_off  = (const float*)d_in[5];
  const float* b_off  = (const float*)d_in[6];
  const float* W_attn = (const float*)d_in[7];
  const float* b_attn = (const float*)d_in[8];
  const float* W_val  = (const float*)d_in[9];
  const float* b_val  = (const float*)d_in[10];
  const float* W_out  = (const float*)d_in[11];
  const float* b_out  = (const float*)d_in[12];
  float* out = (float*)d_out;

  unsigned char* w = (unsigned char*)d_ws;
  unsigned short* Wval_t = (unsigned short*)w;  w += 256 * 256 * 2;
  unsigned short* Woa_t  = (unsigned short*)w;  w += 384 * 256 * 2;
  unsigned short* Wout_t = (unsigned short*)w;  w += 256 * 256 * 2;
  float*          b_oa   = (float*)w;           w += 384 * 4 + 64;
  unsigned short* q_bf   = (unsigned short*)w;  w += (size_t)M_ROWS * 256 * 2;
  unsigned short* in_bf  = (unsigned short*)w;  w += (size_t)M_ROWS * 256 * 2;
  unsigned short* v_buf  = (unsigned short*)w;  w += (size_t)M_ROWS * 256 * 2;
  unsigned short* oa_buf = (unsigned short*)w;  w += (size_t)M_ROWS * 384 * 2;
  unsigned int*   mid_buf = (unsigned int*)w;   // M*128 u32

  const dim3 blk(256);
  const int mg = (M_ROWS + 127) / 128;   // 208

  prep_all<<<dim3(CONV_BLKS + 896), blk, 0, stream>>>(
      query, inpf, W_off, b_off, W_attn, b_attn, W_val, W_out,
      q_bf, in_bf, Wval_t, Woa_t, Wout_t, b_oa);
  // value = input @ W_val + b_val -> bf16
  gemm_mfma<1><<<dim3(mg, 2), blk, 0, stream>>>(in_bf, Wval_t, b_val, v_buf,
                                                M_ROWS, 256);
  // off|logits = query @ [W_off|W_attn] + b -> fp16
  gemm_mfma<2><<<dim3(mg, 3), blk, 0, stream>>>(q_bf, Woa_t, b_oa, oa_buf,
                                                M_ROWS, 384);
  // softmax + bilinear sampling -> mid (bf16 pairs)
  sample_kernel<<<dim3(M_ROWS / 4), blk, 0, stream>>>(refp, oa_buf, v_buf,
                                                      mid_buf);
  // out = mid @ W_out + b_out -> fp32
  gemm_mfma<0><<<dim3(mg, 2), blk, 0, stream>>>((const unsigned short*)mid_buf,
                                                Wout_t, b_out, out, M_ROWS, 256);
}

// Round 4
// 214.188 us; speedup vs baseline: 1.7644x; 1.0451x over previous
//
#include <hip/hip_runtime.h>
#include <math.h>

// ---- problem constants ----
#define BQ 2
#define LQ 13294
#define LEN_IN 13294
#define M_ROWS 26588          // BQ*LQ

__device__ __constant__ int c_HW[4]    = {100, 50, 25, 13};
__device__ __constant__ int c_START[4] = {0, 10000, 12500, 13125};

typedef __attribute__((ext_vector_type(8))) short bf16x8;
typedef __attribute__((ext_vector_type(4))) float f32x4;

__device__ inline unsigned short f2bf(float f) {
  union { float f; unsigned int u; } x; x.f = f;
  unsigned int u = x.u;
  return (unsigned short)((u + 0x7fffu + ((u >> 16) & 1u)) >> 16);
}
__device__ inline float h2f(unsigned short h) {
  _Float16 x; __builtin_memcpy(&x, &h, 2); return (float)x;
}
__device__ inline unsigned short f2h(float f) {
  _Float16 x = (_Float16)f; unsigned short u; __builtin_memcpy(&u, &x, 2); return u;
}

__device__ inline void gl_lds16(const void* g, void* l) {
  __builtin_amdgcn_global_load_lds(
      (const __attribute__((address_space(1))) unsigned int*)g,
      (__attribute__((address_space(3))) unsigned int*)l, 16, 0, 0);
}

// ---------------------------------------------------------------------------
// Fused prep: fp32->bf16 conversion of query & input_flatten + weight
// transpose/convert to bf16 [N][K] + fused oa bias.
// ---------------------------------------------------------------------------
#define CONV_BLKS 3456
#define N4EACH (M_ROWS * 64)   // float4s per matrix

__global__ __launch_bounds__(256) void prep_all(
    const float* __restrict__ query, const float* __restrict__ inpf,
    const float* __restrict__ W_off, const float* __restrict__ b_off,
    const float* __restrict__ W_attn, const float* __restrict__ b_attn,
    const float* __restrict__ W_val, const float* __restrict__ W_out,
    unsigned short* __restrict__ q_bf, unsigned short* __restrict__ in_bf,
    unsigned short* __restrict__ Wval_t, unsigned short* __restrict__ Woa_t,
    unsigned short* __restrict__ Wout_t, float* __restrict__ b_oa) {
  const int bx = blockIdx.x;
  if (bx < CONV_BLKS) {
    int i = bx * 256 + threadIdx.x;
    const int stride = CONV_BLKS * 256;
    for (; i < 2 * N4EACH; i += stride) {
      const float* src; unsigned short* dst; int j;
      if (i < N4EACH) { src = query; dst = q_bf; j = i; }
      else            { src = inpf;  dst = in_bf; j = i - N4EACH; }
      const float4 v = ((const float4*)src)[j];
      ushort4 h;
      h.x = f2bf(v.x); h.y = f2bf(v.y); h.z = f2bf(v.z); h.w = f2bf(v.w);
      ((ushort4*)dst)[j] = h;
    }
    return;
  }
  const int idx = (bx - CONV_BLKS) * 256 + threadIdx.x;
  const int SZ1 = 256 * 256;
  const int SZ2 = 384 * 256;
  if (idx < SZ1) {
    const int n = idx >> 8, k = idx & 255;
    Wval_t[idx] = f2bf(W_val[k * 256 + n]);
  } else if (idx < SZ1 + SZ2) {
    const int j = idx - SZ1;
    const int n = j >> 8, k = j & 255;
    const float v = (n < 256) ? W_off[k * 256 + n] : W_attn[k * 128 + (n - 256)];
    Woa_t[j] = f2bf(v);
  } else {
    const int j = idx - SZ1 - SZ2;
    const int n = j >> 8, k = j & 255;
    Wout_t[j] = f2bf(W_out[k * 256 + n]);
  }
  if (bx == CONV_BLKS) b_oa[threadIdx.x] = b_off[threadIdx.x];
  if (bx == CONV_BLKS + 1 && threadIdx.x < 128)
    b_oa[256 + threadIdx.x] = b_attn[threadIdx.x];
}

// ---------------------------------------------------------------------------
// bf16 MFMA GEMM core with OPERAND-SWAPPED accumulate:
//   acc[i][j] = mfma(b_frag[j], a_frag[i], acc)  ->  lane&15 = m (fixed),
//   (lane>>4)*4+reg = 4 consecutive n  => fully vectorized epilogue stores.
// 128x128 tile, BK=64, global_load_lds dwordx4 staging, XOR-swizzled LDS.
// CT: 0 = fp32 C, 1 = bf16 C, 2 = fp16 C.
// ---------------------------------------------------------------------------
template <int CT>
__device__ inline void gemm_body(
    const unsigned short* __restrict__ A, const unsigned short* __restrict__ Wt,
    const float* __restrict__ bias, void* __restrict__ Cp,
    int M, int N, int m0, int n0,
    unsigned short* As, unsigned short* Bs) {
  const int tid = threadIdx.x;
  const int wv = tid >> 6;
  const int lane = tid & 63;
  const int wm = (wv & 1) * 64;
  const int wn = (wv >> 1) * 64;
  const int fr = lane & 15;
  const int fq = lane >> 4;
  const int lr = lane >> 3;
  const int gch = (lane & 7) ^ lr;

  const unsigned short* ga[4];
  const unsigned short* gb[4];
#pragma unroll
  for (int t = 0; t < 4; ++t) {
    int ar = m0 + wv * 32 + t * 8 + lr;
    if (ar > M - 1) ar = M - 1;
    ga[t] = A + (size_t)ar * 256 + gch * 8;
    gb[t] = Wt + (size_t)(n0 + wv * 32 + t * 8 + lr) * 256 + gch * 8;
  }

  f32x4 acc[4][4];
#pragma unroll
  for (int i = 0; i < 4; ++i)
#pragma unroll
    for (int j = 0; j < 4; ++j) acc[i][j] = (f32x4){0.f, 0.f, 0.f, 0.f};

  for (int k0 = 0; k0 < 256; k0 += 64) {
    __syncthreads();
#pragma unroll
    for (int t = 0; t < 4; ++t) {
      gl_lds16(ga[t], &As[(wv * 32 + t * 8) * 64]);
      gl_lds16(gb[t], &Bs[(wv * 32 + t * 8) * 64]);
      ga[t] += 64; gb[t] += 64;
    }
    __syncthreads();
#pragma unroll
    for (int kk = 0; kk < 2; ++kk) {
      bf16x8 af[4], bf[4];
#pragma unroll
      for (int i = 0; i < 4; ++i) {
        const int row = wm + i * 16 + fr;
        af[i] = *(const bf16x8*)&As[row * 64 + ((kk * 4 + fq) ^ (row & 7)) * 8];
      }
#pragma unroll
      for (int j = 0; j < 4; ++j) {
        const int row = wn + j * 16 + fr;
        bf[j] = *(const bf16x8*)&Bs[row * 64 + ((kk * 4 + fq) ^ (row & 7)) * 8];
      }
#pragma unroll
      for (int i = 0; i < 4; ++i)
#pragma unroll
        for (int j = 0; j < 4; ++j)
          acc[i][j] = __builtin_amdgcn_mfma_f32_16x16x32_bf16(bf[j], af[i],
                                                              acc[i][j], 0, 0, 0);
    }
  }

  // Epilogue: lane owns row m = m0+wm+i*16+fr, cols n0+wn+j*16+fq*4 .. +3.
#pragma unroll
  for (int j = 0; j < 4; ++j) {
    const int nb = n0 + wn + j * 16 + fq * 4;
    const float4 b4 = *(const float4*)&bias[nb];
#pragma unroll
    for (int i = 0; i < 4; ++i) {
      const int m = m0 + wm + i * 16 + fr;
      if (m >= M) continue;
      const float v0 = acc[i][j][0] + b4.x;
      const float v1 = acc[i][j][1] + b4.y;
      const float v2 = acc[i][j][2] + b4.z;
      const float v3 = acc[i][j][3] + b4.w;
      if (CT == 0) {
        float4 o = make_float4(v0, v1, v2, v3);
        *(float4*)&((float*)Cp)[(size_t)m * N + nb] = o;
      } else if (CT == 1) {
        uint2 o;
        o.x = (unsigned int)f2bf(v0) | ((unsigned int)f2bf(v1) << 16);
        o.y = (unsigned int)f2bf(v2) | ((unsigned int)f2bf(v3) << 16);
        *(uint2*)&((unsigned short*)Cp)[(size_t)m * N + nb] = o;
      } else {
        uint2 o;
        o.x = (unsigned int)f2h(v0) | ((unsigned int)f2h(v1) << 16);
        o.y = (unsigned int)f2h(v2) | ((unsigned int)f2h(v3) << 16);
        *(uint2*)&((unsigned short*)Cp)[(size_t)m * N + nb] = o;
      }
    }
  }
}

// Fused: blockIdx.y 0-1 -> value GEMM (N=256, bf16 C); 2-4 -> oa (N=384, fp16 C)
__global__ __launch_bounds__(256) void gemm_fused(
    const unsigned short* __restrict__ in_bf,
    const unsigned short* __restrict__ q_bf,
    const unsigned short* __restrict__ Wval_t,
    const unsigned short* __restrict__ Woa_t,
    const float* __restrict__ b_val, const float* __restrict__ b_oa,
    void* __restrict__ v_buf, void* __restrict__ oa_buf) {
  __shared__ unsigned short As[128 * 64];
  __shared__ unsigned short Bs[128 * 64];
  const int m0 = blockIdx.x * 128;
  if (blockIdx.y < 2) {
    gemm_body<1>(in_bf, Wval_t, b_val, v_buf, M_ROWS, 256,
                 m0, blockIdx.y * 128, As, Bs);
  } else {
    gemm_body<2>(q_bf, Woa_t, b_oa, oa_buf, M_ROWS, 384,
                 m0, (blockIdx.y - 2) * 128, As, Bs);
  }
}

__global__ __launch_bounds__(256) void gemm_out(
    const unsigned short* __restrict__ mid,
    const unsigned short* __restrict__ Wout_t,
    const float* __restrict__ b_out, float* __restrict__ out) {
  __shared__ unsigned short As[128 * 64];
  __shared__ unsigned short Bs[128 * 64];
  gemm_body<0>(mid, Wout_t, b_out, out, M_ROWS, 256,
               blockIdx.x * 128, blockIdx.y * 128, As, Bs);
}

// ---------------------------------------------------------------------------
// Sampler (Round-2 proven structure + fp16 oa): 2 queries/block, 256 threads.
// Phase A: per-point softmax (16-lane shuffles) + tap {weight, byteoff} -> LDS.
// Phase B: 128 thr/query, thread owns (head, d-pair): 64 taps, each one
//   ds_read_b64 + one u32 (2 bf16) global load.
// ---------------------------------------------------------------------------
__global__ __launch_bounds__(256) void sample_kernel(
    const float* __restrict__ refp,           // (B,LQ,4,2) fp32
    const unsigned short* __restrict__ oa,    // (M,384) fp16: off|logits
    const unsigned short* __restrict__ value, // (M,256) bf16
    unsigned int* __restrict__ mid) {         // (M,128) u32 bf16-pairs
  const int tid = threadIdx.x;
  const int qi = tid >> 7;
  const int q = blockIdx.x * 2 + qi;
  const int b = (q >= LQ) ? 1 : 0;

  __shared__ float2 s_wo[2][4][136];          // [qi][tap][h*17+lp]

  // ---- Phase A ----
  {
    const int pid = tid & 127;                // h*16 + l*4 + p
    const int h = pid >> 4;
    const int lp = pid & 15;
    const int l = lp >> 2;
    const int p = lp & 3;
    const int HW = c_HW[l];
    const float fW = (float)HW;

    const float logit = h2f(oa[(size_t)q * 384 + 256 + pid]);
    float mx = logit;
#pragma unroll
    for (int s = 1; s < 16; s <<= 1) mx = fmaxf(mx, __shfl_xor(mx, s, 16));
    const float e = expf(logit - mx);
    float sum = e;
#pragma unroll
    for (int s = 1; s < 16; s <<= 1) sum += __shfl_xor(sum, s, 16);
    const float a = e / sum;

    const unsigned int opk =
        *(const unsigned int*)&oa[(size_t)q * 384 + h * 32 + l * 8 + p * 2];
    const float ox = h2f((unsigned short)(opk & 0xffffu));
    const float oy = h2f((unsigned short)(opk >> 16));
    const float rx = refp[((size_t)q * 4 + l) * 2 + 0];
    const float ry = refp[((size_t)q * 4 + l) * 2 + 1];
    const float x = (rx + ox / fW) * fW - 0.5f;
    const float y = (ry + oy / fW) * fW - 0.5f;
    const float x0 = floorf(x);
    const float y0 = floorf(y);

#pragma unroll
    for (int t = 0; t < 4; ++t) {
      const int dx = t & 1;
      const int dy = t >> 1;
      const float xi = x0 + (float)dx;
      const float yi = y0 + (float)dy;
      const float wgt = (1.0f - fabsf(x - xi)) * (1.0f - fabsf(y - yi));
      const bool valid =
          (xi >= 0.f) && (xi <= fW - 1.f) && (yi >= 0.f) && (yi <= fW - 1.f);
      int xc = (int)xi; xc = xc < 0 ? 0 : (xc > HW - 1 ? HW - 1 : xc);
      int yc = (int)yi; yc = yc < 0 ? 0 : (yc > HW - 1 ? HW - 1 : yc);
      const int row = b * LEN_IN + c_START[l] + yc * HW + xc;
      float2 wo;
      wo.x = valid ? wgt * a : 0.f;
      wo.y = __int_as_float(row * 512 + h * 64);  // bf16 row = 512 B
      s_wo[qi][t][h * 17 + lp] = wo;
    }
  }
  __syncthreads();

  // ---- Phase B ----
  {
    const int g = tid & 127;
    const int h = g >> 4;
    const int dp = g & 15;                    // d-pair
    const char* vbase = (const char*)value + dp * 4;
    float acc0 = 0.f, acc1 = 0.f;
#pragma unroll 4
    for (int lp = 0; lp < 16; ++lp) {
      const int si = h * 17 + lp;
#pragma unroll
      for (int t = 0; t < 4; ++t) {
        const float2 f = s_wo[qi][t][si];
        const unsigned int v = *(const unsigned int*)(vbase + __float_as_int(f.y));
        acc0 += f.x * __uint_as_float(v << 16);
        acc1 += f.x * __uint_as_float(v & 0xffff0000u);
      }
    }
    mid[(size_t)q * 128 + h * 16 + dp] =
        (unsigned int)f2bf(acc0) | ((unsigned int)f2bf(acc1) << 16);
  }
}

// ---------------------------------------------------------------------------
extern "C" void kernel_launch(void* const* d_in, const int* in_sizes, int n_in,
                              void* d_out, int out_size, void* d_ws,
                              size_t ws_size, hipStream_t stream) {
  const float* query  = (const float*)d_in[0];
  const float* refp   = (const float*)d_in[1];
  const float* inpf   = (const float*)d_in[2];
  const float* W_off  = (const float*)d_in[5];
  const float* b_off  = (const float*)d_in[6];
  const float* W_attn = (const float*)d_in[7];
  const float* b_attn = (const float*)d_in[8];
  const float* W_val  = (const float*)d_in[9];
  const float* b_val  = (const float*)d_in[10];
  const float* W_out  = (const float*)d_in[11];
  const float* b_out  = (const float*)d_in[12];
  float* out = (float*)d_out;

  unsigned char* w = (unsigned char*)d_ws;
  unsigned short* Wval_t = (unsigned short*)w;  w += 256 * 256 * 2;
  unsigned short* Woa_t  = (unsigned short*)w;  w += 384 * 256 * 2;
  unsigned short* Wout_t = (unsigned short*)w;  w += 256 * 256 * 2;
  float*          b_oa   = (float*)w;           w += 384 * 4 + 64;
  unsigned short* q_bf   = (unsigned short*)w;  w += (size_t)M_ROWS * 256 * 2;
  unsigned short* in_bf  = (unsigned short*)w;  w += (size_t)M_ROWS * 256 * 2;
  unsigned short* v_buf  = (unsigned short*)w;  w += (size_t)M_ROWS * 256 * 2;
  unsigned short* oa_buf = (unsigned short*)w;  w += (size_t)M_ROWS * 384 * 2;
  unsigned int*   mid_buf = (unsigned int*)w;   // M*128 u32

  const dim3 blk(256);
  const int mg = (M_ROWS + 127) / 128;   // 208

  prep_all<<<dim3(CONV_BLKS + 896), blk, 0, stream>>>(
      query, inpf, W_off, b_off, W_attn, b_attn, W_val, W_out,
      q_bf, in_bf, Wval_t, Woa_t, Wout_t, b_oa);
  // value -> bf16 ; off|logits -> fp16 (fused)
  gemm_fused<<<dim3(mg, 5), blk, 0, stream>>>(in_bf, q_bf, Wval_t, Woa_t,
                                              b_val, b_oa, v_buf, oa_buf);
  // softmax + bilinear sampling -> mid (bf16 pairs)
  sample_kernel<<<dim3(M_ROWS / 2), blk, 0, stream>>>(refp, oa_buf, v_buf,
                                                      mid_buf);
  // out = mid @ W_out + b_out -> fp32
  gemm_out<<<dim3(mg, 2), blk, 0, stream>>>((const unsigned short*)mid_buf,
                                            Wout_t, b_out, out);
}

// Round 5
// 212.627 us; speedup vs baseline: 1.7774x; 1.0073x over previous
//
#include <hip/hip_runtime.h>
#include <math.h>

// ---- problem constants ----
#define BQ 2
#define LQ 13294
#define LEN_IN 13294
#define M_ROWS 26588          // BQ*LQ

__device__ __constant__ int c_HW[4]    = {100, 50, 25, 13};
__device__ __constant__ int c_START[4] = {0, 10000, 12500, 13125};

typedef __attribute__((ext_vector_type(8))) short bf16x8;
typedef __attribute__((ext_vector_type(4))) float f32x4;

__device__ inline unsigned short f2bf(float f) {
  union { float f; unsigned int u; } x; x.f = f;
  unsigned int u = x.u;
  return (unsigned short)((u + 0x7fffu + ((u >> 16) & 1u)) >> 16);
}
__device__ inline float h2f(unsigned short h) {
  _Float16 x; __builtin_memcpy(&x, &h, 2); return (float)x;
}
__device__ inline unsigned short f2h(float f) {
  _Float16 x = (_Float16)f; unsigned short u; __builtin_memcpy(&u, &x, 2); return u;
}

__device__ inline void gl_lds16(const void* g, void* l) {
  __builtin_amdgcn_global_load_lds(
      (const __attribute__((address_space(1))) unsigned int*)g,
      (__attribute__((address_space(3))) unsigned int*)l, 16, 0, 0);
}

// ---------------------------------------------------------------------------
// Fused prep: fp32->bf16 conversion of query & input_flatten + weight
// transpose/convert to bf16 [N][K] + fused oa bias.
// ---------------------------------------------------------------------------
#define CONV_BLKS 3456
#define N4EACH (M_ROWS * 64)   // float4s per matrix

__global__ __launch_bounds__(256) void prep_all(
    const float* __restrict__ query, const float* __restrict__ inpf,
    const float* __restrict__ W_off, const float* __restrict__ b_off,
    const float* __restrict__ W_attn, const float* __restrict__ b_attn,
    const float* __restrict__ W_val, const float* __restrict__ W_out,
    unsigned short* __restrict__ q_bf, unsigned short* __restrict__ in_bf,
    unsigned short* __restrict__ Wval_t, unsigned short* __restrict__ Woa_t,
    unsigned short* __restrict__ Wout_t, float* __restrict__ b_oa) {
  const int bx = blockIdx.x;
  if (bx < CONV_BLKS) {
    int i = bx * 256 + threadIdx.x;
    const int stride = CONV_BLKS * 256;
    for (; i < 2 * N4EACH; i += stride) {
      const float* src; unsigned short* dst; int j;
      if (i < N4EACH) { src = query; dst = q_bf; j = i; }
      else            { src = inpf;  dst = in_bf; j = i - N4EACH; }
      const float4 v = ((const float4*)src)[j];
      ushort4 h;
      h.x = f2bf(v.x); h.y = f2bf(v.y); h.z = f2bf(v.z); h.w = f2bf(v.w);
      ((ushort4*)dst)[j] = h;
    }
    return;
  }
  const int idx = (bx - CONV_BLKS) * 256 + threadIdx.x;
  const int SZ1 = 256 * 256;
  const int SZ2 = 384 * 256;
  if (idx < SZ1) {
    const int n = idx >> 8, k = idx & 255;
    Wval_t[idx] = f2bf(W_val[k * 256 + n]);
  } else if (idx < SZ1 + SZ2) {
    const int j = idx - SZ1;
    const int n = j >> 8, k = j & 255;
    const float v = (n < 256) ? W_off[k * 256 + n] : W_attn[k * 128 + (n - 256)];
    Woa_t[j] = f2bf(v);
  } else {
    const int j = idx - SZ1 - SZ2;
    const int n = j >> 8, k = j & 255;
    Wout_t[j] = f2bf(W_out[k * 256 + n]);
  }
  if (bx == CONV_BLKS) b_oa[threadIdx.x] = b_off[threadIdx.x];
  if (bx == CONV_BLKS + 1 && threadIdx.x < 128)
    b_oa[256 + threadIdx.x] = b_attn[threadIdx.x];
}

// ---------------------------------------------------------------------------
// Barrier-free streaming GEMM for K=256, tall M:
//  - W slice [n0..n0+127] x 256 staged ONCE in LDS (64 KB, XOR-swizzled
//    16B chunks: phys = chunk ^ (row&7) -> 2-way-max bank aliasing, free).
//  - A read straight into MFMA A-fragments from global (lane = 16B bf16x8 at
//    row (m + lane&15), k = kk*32 + (lane>>4)*8): 8 k-steps cover the whole
//    512B row, no LDS round-trip, NO __syncthreads in the K-loop.
//  - operand-swapped mfma(b,a,acc): lane&15 = m, (lane>>4)*4+reg = 4
//    consecutive n -> vectorized stores.
//  Wave covers 32 m-rows (2 MFMA m-tiles) x 128 n; block = 4 waves = 128 rows.
// CT: 0 = fp32 C, 1 = bf16 C, 2 = fp16 C.
// ---------------------------------------------------------------------------
template <int CT>
__device__ inline void gemm_stream(
    const unsigned short* __restrict__ A, const unsigned short* __restrict__ Wt,
    const float* __restrict__ bias, void* __restrict__ Cp,
    int M, int N, int m0, int n0, unsigned short* Ws) {
  const int tid = threadIdx.x;
  const int wv = tid >> 6;
  const int lane = tid & 63;
  const int fr = lane & 15;
  const int fq = lane >> 4;

  // ---- stage W slice (128 x 256 bf16 = 64 KB) ----
#pragma unroll
  for (int it = 0; it < 16; ++it) {
    const int lin = wv * 1024 + it * 64 + lane;   // 16B-chunk linear index
    const int r = lin >> 5;                        // W row 0..127
    const int p = lin & 31;                        // physical chunk in row
    const int c = p ^ (r & 7);                     // logical chunk fetched
    gl_lds16(Wt + (size_t)(n0 + r) * 256 + c * 8,
             &Ws[(size_t)(wv * 1024 + it * 64) * 8]);
  }
  __syncthreads();   // the only barrier

  // ---- A fragment pointers (rows clamped; stores masked) ----
  int mr0 = m0 + wv * 32 + fr;       if (mr0 > M - 1) mr0 = M - 1;
  int mr1 = m0 + wv * 32 + 16 + fr;  if (mr1 > M - 1) mr1 = M - 1;
  const unsigned short* a0 = A + (size_t)mr0 * 256 + fq * 8;
  const unsigned short* a1 = A + (size_t)mr1 * 256 + fq * 8;

  f32x4 acc[2][8];
#pragma unroll
  for (int mt = 0; mt < 2; ++mt)
#pragma unroll
    for (int n = 0; n < 8; ++n) acc[mt][n] = (f32x4){0.f, 0.f, 0.f, 0.f};

#pragma unroll
  for (int kk = 0; kk < 8; ++kk) {
    const bf16x8 af0 = *(const bf16x8*)(a0 + kk * 32);
    const bf16x8 af1 = *(const bf16x8*)(a1 + kk * 32);
#pragma unroll
    for (int n = 0; n < 8; ++n) {
      const int rn = n * 16 + fr;
      const bf16x8 b =
          *(const bf16x8*)&Ws[rn * 256 + (((kk * 4 + fq) ^ (rn & 7)) * 8)];
      acc[0][n] = __builtin_amdgcn_mfma_f32_16x16x32_bf16(b, af0, acc[0][n], 0, 0, 0);
      acc[1][n] = __builtin_amdgcn_mfma_f32_16x16x32_bf16(b, af1, acc[1][n], 0, 0, 0);
    }
  }

  // ---- epilogue: lane&15 = m, fq*4 = 4 consecutive n ----
#pragma unroll
  for (int n = 0; n < 8; ++n) {
    const int nb = n0 + n * 16 + fq * 4;
    const float4 b4 = *(const float4*)&bias[nb];
#pragma unroll
    for (int mt = 0; mt < 2; ++mt) {
      const int m = m0 + wv * 32 + mt * 16 + fr;
      if (m >= M) continue;
      const float v0 = acc[mt][n][0] + b4.x;
      const float v1 = acc[mt][n][1] + b4.y;
      const float v2 = acc[mt][n][2] + b4.z;
      const float v3 = acc[mt][n][3] + b4.w;
      if (CT == 0) {
        *(float4*)&((float*)Cp)[(size_t)m * N + nb] = make_float4(v0, v1, v2, v3);
      } else if (CT == 1) {
        uint2 o;
        o.x = (unsigned int)f2bf(v0) | ((unsigned int)f2bf(v1) << 16);
        o.y = (unsigned int)f2bf(v2) | ((unsigned int)f2bf(v3) << 16);
        *(uint2*)&((unsigned short*)Cp)[(size_t)m * N + nb] = o;
      } else {
        uint2 o;
        o.x = (unsigned int)f2h(v0) | ((unsigned int)f2h(v1) << 16);
        o.y = (unsigned int)f2h(v2) | ((unsigned int)f2h(v3) << 16);
        *(uint2*)&((unsigned short*)Cp)[(size_t)m * N + nb] = o;
      }
    }
  }
}

// value (y 0-1, N=256, bf16 C) + oa (y 2-4, N=384, fp16 C) fused.
__global__ __launch_bounds__(256) void gemm_vo(
    const unsigned short* __restrict__ in_bf,
    const unsigned short* __restrict__ q_bf,
    const unsigned short* __restrict__ Wval_t,
    const unsigned short* __restrict__ Woa_t,
    const float* __restrict__ b_val, const float* __restrict__ b_oa,
    void* __restrict__ v_buf, void* __restrict__ oa_buf) {
  __shared__ unsigned short Ws[128 * 256];
  const int m0 = blockIdx.x * 128;
  if (blockIdx.y < 2) {
    gemm_stream<1>(in_bf, Wval_t, b_val, v_buf, M_ROWS, 256,
                   m0, blockIdx.y * 128, Ws);
  } else {
    gemm_stream<2>(q_bf, Woa_t, b_oa, oa_buf, M_ROWS, 384,
                   m0, (blockIdx.y - 2) * 128, Ws);
  }
}

__global__ __launch_bounds__(256) void gemm_out(
    const unsigned short* __restrict__ mid,
    const unsigned short* __restrict__ Wout_t,
    const float* __restrict__ b_out, float* __restrict__ out) {
  __shared__ unsigned short Ws[128 * 256];
  gemm_stream<0>(mid, Wout_t, b_out, out, M_ROWS, 256,
                 blockIdx.x * 128, blockIdx.y * 128, Ws);
}

// ---------------------------------------------------------------------------
// Sampler (unchanged from R4): 2 queries/block, 256 threads.
// ---------------------------------------------------------------------------
__global__ __launch_bounds__(256) void sample_kernel(
    const float* __restrict__ refp,           // (B,LQ,4,2) fp32
    const unsigned short* __restrict__ oa,    // (M,384) fp16: off|logits
    const unsigned short* __restrict__ value, // (M,256) bf16
    unsigned int* __restrict__ mid) {         // (M,128) u32 bf16-pairs
  const int tid = threadIdx.x;
  const int qi = tid >> 7;
  const int q = blockIdx.x * 2 + qi;
  const int b = (q >= LQ) ? 1 : 0;

  __shared__ float2 s_wo[2][4][136];          // [qi][tap][h*17+lp]

  // ---- Phase A ----
  {
    const int pid = tid & 127;                // h*16 + l*4 + p
    const int h = pid >> 4;
    const int lp = pid & 15;
    const int l = lp >> 2;
    const int p = lp & 3;
    const int HW = c_HW[l];
    const float fW = (float)HW;

    const float logit = h2f(oa[(size_t)q * 384 + 256 + pid]);
    float mx = logit;
#pragma unroll
    for (int s = 1; s < 16; s <<= 1) mx = fmaxf(mx, __shfl_xor(mx, s, 16));
    const float e = expf(logit - mx);
    float sum = e;
#pragma unroll
    for (int s = 1; s < 16; s <<= 1) sum += __shfl_xor(sum, s, 16);
    const float a = e / sum;

    const unsigned int opk =
        *(const unsigned int*)&oa[(size_t)q * 384 + h * 32 + l * 8 + p * 2];
    const float ox = h2f((unsigned short)(opk & 0xffffu));
    const float oy = h2f((unsigned short)(opk >> 16));
    const float rx = refp[((size_t)q * 4 + l) * 2 + 0];
    const float ry = refp[((size_t)q * 4 + l) * 2 + 1];
    const float x = (rx + ox / fW) * fW - 0.5f;
    const float y = (ry + oy / fW) * fW - 0.5f;
    const float x0 = floorf(x);
    const float y0 = floorf(y);

#pragma unroll
    for (int t = 0; t < 4; ++t) {
      const int dx = t & 1;
      const int dy = t >> 1;
      const float xi = x0 + (float)dx;
      const float yi = y0 + (float)dy;
      const float wgt = (1.0f - fabsf(x - xi)) * (1.0f - fabsf(y - yi));
      const bool valid =
          (xi >= 0.f) && (xi <= fW - 1.f) && (yi >= 0.f) && (yi <= fW - 1.f);
      int xc = (int)xi; xc = xc < 0 ? 0 : (xc > HW - 1 ? HW - 1 : xc);
      int yc = (int)yi; yc = yc < 0 ? 0 : (yc > HW - 1 ? HW - 1 : yc);
      const int row = b * LEN_IN + c_START[l] + yc * HW + xc;
      float2 wo;
      wo.x = valid ? wgt * a : 0.f;
      wo.y = __int_as_float(row * 512 + h * 64);  // bf16 row = 512 B
      s_wo[qi][t][h * 17 + lp] = wo;
    }
  }
  __syncthreads();

  // ---- Phase B ----
  {
    const int g = tid & 127;
    const int h = g >> 4;
    const int dp = g & 15;                    // d-pair
    const char* vbase = (const char*)value + dp * 4;
    float acc0 = 0.f, acc1 = 0.f;
#pragma unroll 4
    for (int lp = 0; lp < 16; ++lp) {
      const int si = h * 17 + lp;
#pragma unroll
      for (int t = 0; t < 4; ++t) {
        const float2 f = s_wo[qi][t][si];
        const unsigned int v = *(const unsigned int*)(vbase + __float_as_int(f.y));
        acc0 += f.x * __uint_as_float(v << 16);
        acc1 += f.x * __uint_as_float(v & 0xffff0000u);
      }
    }
    mid[(size_t)q * 128 + h * 16 + dp] =
        (unsigned int)f2bf(acc0) | ((unsigned int)f2bf(acc1) << 16);
  }
}

// ---------------------------------------------------------------------------
extern "C" void kernel_launch(void* const* d_in, const int* in_sizes, int n_in,
                              void* d_out, int out_size, void* d_ws,
                              size_t ws_size, hipStream_t stream) {
  const float* query  = (const float*)d_in[0];
  const float* refp   = (const float*)d_in[1];
  const float* inpf   = (const float*)d_in[2];
  const float* W_off  = (const float*)d_in[5];
  const float* b_off  = (const float*)d_in[6];
  const float* W_attn = (const float*)d_in[7];
  const float* b_attn = (const float*)d_in[8];
  const float* W_val  = (const float*)d_in[9];
  const float* b_val  = (const float*)d_in[10];
  const float* W_out  = (const float*)d_in[11];
  const float* b_out  = (const float*)d_in[12];
  float* out = (float*)d_out;

  unsigned char* w = (unsigned char*)d_ws;
  unsigned short* Wval_t = (unsigned short*)w;  w += 256 * 256 * 2;
  unsigned short* Woa_t  = (unsigned short*)w;  w += 384 * 256 * 2;
  unsigned short* Wout_t = (unsigned short*)w;  w += 256 * 256 * 2;
  float*          b_oa   = (float*)w;           w += 384 * 4 + 64;
  unsigned short* q_bf   = (unsigned short*)w;  w += (size_t)M_ROWS * 256 * 2;
  unsigned short* in_bf  = (unsigned short*)w;  w += (size_t)M_ROWS * 256 * 2;
  unsigned short* v_buf  = (unsigned short*)w;  w += (size_t)M_ROWS * 256 * 2;
  unsigned short* oa_buf = (unsigned short*)w;  w += (size_t)M_ROWS * 384 * 2;
  unsigned int*   mid_buf = (unsigned int*)w;   // M*128 u32

  const dim3 blk(256);
  const int mg = (M_ROWS + 127) / 128;   // 208

  prep_all<<<dim3(CONV_BLKS + 896), blk, 0, stream>>>(
      query, inpf, W_off, b_off, W_attn, b_attn, W_val, W_out,
      q_bf, in_bf, Wval_t, Woa_t, Wout_t, b_oa);
  // value -> bf16 ; off|logits -> fp16 (fused, barrier-free K-loop)
  gemm_vo<<<dim3(mg, 5), blk, 0, stream>>>(in_bf, q_bf, Wval_t, Woa_t,
                                           b_val, b_oa, v_buf, oa_buf);
  // softmax + bilinear sampling -> mid (bf16 pairs)
  sample_kernel<<<dim3(M_ROWS / 2), blk, 0, stream>>>(refp, oa_buf, v_buf,
                                                      mid_buf);
  // out = mid @ W_out + b_out -> fp32
  gemm_out<<<dim3(mg, 2), blk, 0, stream>>>((const unsigned short*)mid_buf,
                                            Wout_t, b_out, out);
}

// Round 6
// 212.524 us; speedup vs baseline: 1.7782x; 1.0005x over previous
//
#include <hip/hip_runtime.h>
#include <math.h>

// ---- problem constants ----
#define BQ 2
#define LQ 13294
#define LEN_IN 13294
#define M_ROWS 26588          // BQ*LQ

__device__ __constant__ int c_HW[4]    = {100, 50, 25, 13};
__device__ __constant__ int c_START[4] = {0, 10000, 12500, 13125};

typedef __attribute__((ext_vector_type(8))) short bf16x8;
typedef __attribute__((ext_vector_type(4))) float f32x4;
typedef __attribute__((ext_vector_type(2))) float f32x2;

__device__ inline unsigned short f2bf(float f) {
  union { float f; unsigned int u; } x; x.f = f;
  unsigned int u = x.u;
  return (unsigned short)((u + 0x7fffu + ((u >> 16) & 1u)) >> 16);
}
__device__ inline float h2f(unsigned short h) {
  _Float16 x; __builtin_memcpy(&x, &h, 2); return (float)x;
}
__device__ inline unsigned short f2h(float f) {
  _Float16 x = (_Float16)f; unsigned short u; __builtin_memcpy(&u, &x, 2); return u;
}

__device__ inline void gl_lds16(const void* g, void* l) {
  __builtin_amdgcn_global_load_lds(
      (const __attribute__((address_space(1))) unsigned int*)g,
      (__attribute__((address_space(3))) unsigned int*)l, 16, 0, 0);
}

// ---------------------------------------------------------------------------
// Fused prep: fp32->bf16 conversion of query & input_flatten + weight
// transpose/convert to bf16 [N][K] + fused oa bias.
// ---------------------------------------------------------------------------
#define CONV_BLKS 3456
#define N4EACH (M_ROWS * 64)   // float4s per matrix

__global__ __launch_bounds__(256) void prep_all(
    const float* __restrict__ query, const float* __restrict__ inpf,
    const float* __restrict__ W_off, const float* __restrict__ b_off,
    const float* __restrict__ W_attn, const float* __restrict__ b_attn,
    const float* __restrict__ W_val, const float* __restrict__ W_out,
    unsigned short* __restrict__ q_bf, unsigned short* __restrict__ in_bf,
    unsigned short* __restrict__ Wval_t, unsigned short* __restrict__ Woa_t,
    unsigned short* __restrict__ Wout_t, float* __restrict__ b_oa) {
  const int bx = blockIdx.x;
  if (bx < CONV_BLKS) {
    int i = bx * 256 + threadIdx.x;
    const int stride = CONV_BLKS * 256;
    for (; i < 2 * N4EACH; i += stride) {
      const float* src; unsigned short* dst; int j;
      if (i < N4EACH) { src = query; dst = q_bf; j = i; }
      else            { src = inpf;  dst = in_bf; j = i - N4EACH; }
      const float4 v = ((const float4*)src)[j];
      ushort4 h;
      h.x = f2bf(v.x); h.y = f2bf(v.y); h.z = f2bf(v.z); h.w = f2bf(v.w);
      ((ushort4*)dst)[j] = h;
    }
    return;
  }
  const int idx = (bx - CONV_BLKS) * 256 + threadIdx.x;
  const int SZ1 = 256 * 256;
  const int SZ2 = 384 * 256;
  if (idx < SZ1) {
    const int n = idx >> 8, k = idx & 255;
    Wval_t[idx] = f2bf(W_val[k * 256 + n]);
  } else if (idx < SZ1 + SZ2) {
    const int j = idx - SZ1;
    const int n = j >> 8, k = j & 255;
    const float v = (n < 256) ? W_off[k * 256 + n] : W_attn[k * 128 + (n - 256)];
    Woa_t[j] = f2bf(v);
  } else {
    const int j = idx - SZ1 - SZ2;
    const int n = j >> 8, k = j & 255;
    Wout_t[j] = f2bf(W_out[k * 256 + n]);
  }
  if (bx == CONV_BLKS) b_oa[threadIdx.x] = b_off[threadIdx.x];
  if (bx == CONV_BLKS + 1 && threadIdx.x < 128)
    b_oa[256 + threadIdx.x] = b_attn[threadIdx.x];
}

// ---------------------------------------------------------------------------
// Streaming GEMM, K=256, with FULL A-PRELOAD for memory-level parallelism:
//  - lane preloads all 16 A fragments (2 m-tiles x 8 k-steps, 256 B) into
//    VGPRs, issued BEFORE the weight-staging DMA -> ~16 KB outstanding/wave.
//  - W slice [n0..n0+127] x 256 staged once in LDS (64 KB, XOR-swizzled).
//  - single barrier; K-loop is pure MFMA + ds_read_b128.
//  - operand-swapped mfma(b,a,acc): lane&15 = m, (lane>>4)*4+reg = 4
//    consecutive n -> vectorized stores.
// CT: 0 = fp32 C, 1 = bf16 C, 2 = fp16 C.
// ---------------------------------------------------------------------------
template <int CT>
__device__ inline void gemm_stream(
    const unsigned short* __restrict__ A, const unsigned short* __restrict__ Wt,
    const float* __restrict__ bias, void* __restrict__ Cp,
    int M, int N, int m0, int n0, unsigned short* Ws) {
  const int tid = threadIdx.x;
  const int wv = tid >> 6;
  const int lane = tid & 63;
  const int fr = lane & 15;
  const int fq = lane >> 4;

  // ---- A fragment preload (2 m-tiles x 8 k-steps), rows clamped ----
  int mr0 = m0 + wv * 32 + fr;       if (mr0 > M - 1) mr0 = M - 1;
  int mr1 = m0 + wv * 32 + 16 + fr;  if (mr1 > M - 1) mr1 = M - 1;
  const unsigned short* a0 = A + (size_t)mr0 * 256 + fq * 8;
  const unsigned short* a1 = A + (size_t)mr1 * 256 + fq * 8;
  bf16x8 a0f[8], a1f[8];
#pragma unroll
  for (int kk = 0; kk < 8; ++kk) {
    a0f[kk] = *(const bf16x8*)(a0 + kk * 32);
    a1f[kk] = *(const bf16x8*)(a1 + kk * 32);
  }

  // ---- stage W slice (128 x 256 bf16 = 64 KB) ----
#pragma unroll
  for (int it = 0; it < 16; ++it) {
    const int lin = wv * 1024 + it * 64 + lane;   // 16B-chunk linear index
    const int r = lin >> 5;                        // W row 0..127
    const int p = lin & 31;                        // physical chunk in row
    const int c = p ^ (r & 7);                     // logical chunk fetched
    gl_lds16(Wt + (size_t)(n0 + r) * 256 + c * 8,
             &Ws[(size_t)(wv * 1024 + it * 64) * 8]);
  }
  __syncthreads();   // the only barrier (drains A preloads too)

  f32x4 acc[2][8];
#pragma unroll
  for (int mt = 0; mt < 2; ++mt)
#pragma unroll
    for (int n = 0; n < 8; ++n) acc[mt][n] = (f32x4){0.f, 0.f, 0.f, 0.f};

#pragma unroll
  for (int kk = 0; kk < 8; ++kk) {
#pragma unroll
    for (int n = 0; n < 8; ++n) {
      const int rn = n * 16 + fr;
      const bf16x8 b =
          *(const bf16x8*)&Ws[rn * 256 + (((kk * 4 + fq) ^ (rn & 7)) * 8)];
      acc[0][n] = __builtin_amdgcn_mfma_f32_16x16x32_bf16(b, a0f[kk], acc[0][n], 0, 0, 0);
      acc[1][n] = __builtin_amdgcn_mfma_f32_16x16x32_bf16(b, a1f[kk], acc[1][n], 0, 0, 0);
    }
  }

  // ---- epilogue: lane&15 = m, fq*4 = 4 consecutive n ----
#pragma unroll
  for (int n = 0; n < 8; ++n) {
    const int nb = n0 + n * 16 + fq * 4;
    const float4 b4 = *(const float4*)&bias[nb];
#pragma unroll
    for (int mt = 0; mt < 2; ++mt) {
      const int m = m0 + wv * 32 + mt * 16 + fr;
      if (m >= M) continue;
      const float v0 = acc[mt][n][0] + b4.x;
      const float v1 = acc[mt][n][1] + b4.y;
      const float v2 = acc[mt][n][2] + b4.z;
      const float v3 = acc[mt][n][3] + b4.w;
      if (CT == 0) {
        *(float4*)&((float*)Cp)[(size_t)m * N + nb] = make_float4(v0, v1, v2, v3);
      } else if (CT == 1) {
        uint2 o;
        o.x = (unsigned int)f2bf(v0) | ((unsigned int)f2bf(v1) << 16);
        o.y = (unsigned int)f2bf(v2) | ((unsigned int)f2bf(v3) << 16);
        *(uint2*)&((unsigned short*)Cp)[(size_t)m * N + nb] = o;
      } else {
        uint2 o;
        o.x = (unsigned int)f2h(v0) | ((unsigned int)f2h(v1) << 16);
        o.y = (unsigned int)f2h(v2) | ((unsigned int)f2h(v3) << 16);
        *(uint2*)&((unsigned short*)Cp)[(size_t)m * N + nb] = o;
      }
    }
  }
}

// value (y 0-1, N=256, bf16 C) + oa (y 2-4, N=384, fp16 C) fused.
__global__ __launch_bounds__(256) void gemm_vo(
    const unsigned short* __restrict__ in_bf,
    const unsigned short* __restrict__ q_bf,
    const unsigned short* __restrict__ Wval_t,
    const unsigned short* __restrict__ Woa_t,
    const float* __restrict__ b_val, const float* __restrict__ b_oa,
    void* __restrict__ v_buf, void* __restrict__ oa_buf) {
  __shared__ unsigned short Ws[128 * 256];
  const int m0 = blockIdx.x * 128;
  if (blockIdx.y < 2) {
    gemm_stream<1>(in_bf, Wval_t, b_val, v_buf, M_ROWS, 256,
                   m0, blockIdx.y * 128, Ws);
  } else {
    gemm_stream<2>(q_bf, Woa_t, b_oa, oa_buf, M_ROWS, 384,
                   m0, (blockIdx.y - 2) * 128, Ws);
  }
}

__global__ __launch_bounds__(256) void gemm_out(
    const unsigned short* __restrict__ mid,
    const unsigned short* __restrict__ Wout_t,
    const float* __restrict__ b_out, float* __restrict__ out) {
  __shared__ unsigned short Ws[128 * 256];
  gemm_stream<0>(mid, Wout_t, b_out, out, M_ROWS, 256,
                 blockIdx.x * 128, blockIdx.y * 128, Ws);
}

// ---------------------------------------------------------------------------
// Sampler: 2 queries/block, 256 threads.
// Phase A: per-point softmax (16-lane shuffles) + tap {weight, byteoff}
//   written as 2 float4 per point -> LDS layout [point][tap].
// Phase B: 128 thr/query, thread owns (head, d-pair): per point 2x
//   ds_read_b128 (4 taps), per tap one u32 load + packed f32x2 FMA.
// ---------------------------------------------------------------------------
__global__ __launch_bounds__(256) void sample_kernel(
    const float* __restrict__ refp,           // (B,LQ,4,2) fp32
    const unsigned short* __restrict__ oa,    // (M,384) fp16: off|logits
    const unsigned short* __restrict__ value, // (M,256) bf16
    unsigned int* __restrict__ mid) {         // (M,128) u32 bf16-pairs
  const int tid = threadIdx.x;
  const int qi = tid >> 7;
  const int q = blockIdx.x * 2 + qi;
  const int b = (q >= LQ) ? 1 : 0;

  __shared__ float4 s_wo[2][136][2];          // [qi][h*17+lp][tap-pair]

  // ---- Phase A ----
  {
    const int pid = tid & 127;                // h*16 + l*4 + p
    const int h = pid >> 4;
    const int lp = pid & 15;
    const int l = lp >> 2;
    const int p = lp & 3;
    const int HW = c_HW[l];
    const float fW = (float)HW;

    const float logit = h2f(oa[(size_t)q * 384 + 256 + pid]);
    float mx = logit;
#pragma unroll
    for (int s = 1; s < 16; s <<= 1) mx = fmaxf(mx, __shfl_xor(mx, s, 16));
    const float e = expf(logit - mx);
    float sum = e;
#pragma unroll
    for (int s = 1; s < 16; s <<= 1) sum += __shfl_xor(sum, s, 16);
    const float a = e / sum;

    const unsigned int opk =
        *(const unsigned int*)&oa[(size_t)q * 384 + h * 32 + l * 8 + p * 2];
    const float ox = h2f((unsigned short)(opk & 0xffffu));
    const float oy = h2f((unsigned short)(opk >> 16));
    const float rx = refp[((size_t)q * 4 + l) * 2 + 0];
    const float ry = refp[((size_t)q * 4 + l) * 2 + 1];
    const float x = (rx + ox / fW) * fW - 0.5f;
    const float y = (ry + oy / fW) * fW - 0.5f;
    const float x0 = floorf(x);
    const float y0 = floorf(y);

    float tw[4]; int toff[4];
#pragma unroll
    for (int t = 0; t < 4; ++t) {
      const int dx = t & 1;
      const int dy = t >> 1;
      const float xi = x0 + (float)dx;
      const float yi = y0 + (float)dy;
      const float wgt = (1.0f - fabsf(x - xi)) * (1.0f - fabsf(y - yi));
      const bool valid =
          (xi >= 0.f) && (xi <= fW - 1.f) && (yi >= 0.f) && (yi <= fW - 1.f);
      int xc = (int)xi; xc = xc < 0 ? 0 : (xc > HW - 1 ? HW - 1 : xc);
      int yc = (int)yi; yc = yc < 0 ? 0 : (yc > HW - 1 ? HW - 1 : yc);
      const int row = b * LEN_IN + c_START[l] + yc * HW + xc;
      tw[t] = valid ? wgt * a : 0.f;
      toff[t] = row * 512 + h * 64;           // bf16 row = 512 B
    }
    float4 p0, p1;
    p0.x = tw[0]; p0.y = __int_as_float(toff[0]);
    p0.z = tw[1]; p0.w = __int_as_float(toff[1]);
    p1.x = tw[2]; p1.y = __int_as_float(toff[2]);
    p1.z = tw[3]; p1.w = __int_as_float(toff[3]);
    s_wo[qi][h * 17 + lp][0] = p0;
    s_wo[qi][h * 17 + lp][1] = p1;
  }
  __syncthreads();

  // ---- Phase B ----
  {
    const int g = tid & 127;
    const int h = g >> 4;
    const int dp = g & 15;                    // d-pair
    const char* vbase = (const char*)value + dp * 4;
    f32x2 acc = {0.f, 0.f};
#pragma unroll 4
    for (int lp = 0; lp < 16; ++lp) {
      const int si = h * 17 + lp;
      const float4 p0 = s_wo[qi][si][0];
      const float4 p1 = s_wo[qi][si][1];
      {
        const unsigned int v = *(const unsigned int*)(vbase + __float_as_int(p0.y));
        f32x2 av = {__uint_as_float(v << 16), __uint_as_float(v & 0xffff0000u)};
        acc += p0.x * av;
      }
      {
        const unsigned int v = *(const unsigned int*)(vbase + __float_as_int(p0.w));
        f32x2 av = {__uint_as_float(v << 16), __uint_as_float(v & 0xffff0000u)};
        acc += p0.z * av;
      }
      {
        const unsigned int v = *(const unsigned int*)(vbase + __float_as_int(p1.y));
        f32x2 av = {__uint_as_float(v << 16), __uint_as_float(v & 0xffff0000u)};
        acc += p1.x * av;
      }
      {
        const unsigned int v = *(const unsigned int*)(vbase + __float_as_int(p1.w));
        f32x2 av = {__uint_as_float(v << 16), __uint_as_float(v & 0xffff0000u)};
        acc += p1.z * av;
      }
    }
    mid[(size_t)q * 128 + h * 16 + dp] =
        (unsigned int)f2bf(acc.x) | ((unsigned int)f2bf(acc.y) << 16);
  }
}

// ---------------------------------------------------------------------------
extern "C" void kernel_launch(void* const* d_in, const int* in_sizes, int n_in,
                              void* d_out, int out_size, void* d_ws,
                              size_t ws_size, hipStream_t stream) {
  const float* query  = (const float*)d_in[0];
  const float* refp   = (const float*)d_in[1];
  const float* inpf   = (const float*)d_in[2];
  const float* W_off  = (const float*)d_in[5];
  const float* b_off  = (const float*)d_in[6];
  const float* W_attn = (const float*)d_in[7];
  const float* b_attn = (const float*)d_in[8];
  const float* W_val  = (const float*)d_in[9];
  const float* b_val  = (const float*)d_in[10];
  const float* W_out  = (const float*)d_in[11];
  const float* b_out  = (const float*)d_in[12];
  float* out = (float*)d_out;

  unsigned char* w = (unsigned char*)d_ws;
  unsigned short* Wval_t = (unsigned short*)w;  w += 256 * 256 * 2;
  unsigned short* Woa_t  = (unsigned short*)w;  w += 384 * 256 * 2;
  unsigned short* Wout_t = (unsigned short*)w;  w += 256 * 256 * 2;
  float*          b_oa   = (float*)w;           w += 384 * 4 + 64;
  unsigned short* q_bf   = (unsigned short*)w;  w += (size_t)M_ROWS * 256 * 2;
  unsigned short* in_bf  = (unsigned short*)w;  w += (size_t)M_ROWS * 256 * 2;
  unsigned short* v_buf  = (unsigned short*)w;  w += (size_t)M_ROWS * 256 * 2;
  unsigned short* oa_buf = (unsigned short*)w;  w += (size_t)M_ROWS * 384 * 2;
  unsigned int*   mid_buf = (unsigned int*)w;   // M*128 u32

  const dim3 blk(256);
  const int mg = (M_ROWS + 127) / 128;   // 208

  prep_all<<<dim3(CONV_BLKS + 896), blk, 0, stream>>>(
      query, inpf, W_off, b_off, W_attn, b_attn, W_val, W_out,
      q_bf, in_bf, Wval_t, Woa_t, Wout_t, b_oa);
  // value -> bf16 ; off|logits -> fp16 (fused, A-preload streaming K-loop)
  gemm_vo<<<dim3(mg, 5), blk, 0, stream>>>(in_bf, q_bf, Wval_t, Woa_t,
                                           b_val, b_oa, v_buf, oa_buf);
  // softmax + bilinear sampling -> mid (bf16 pairs)
  sample_kernel<<<dim3(M_ROWS / 2), blk, 0, stream>>>(refp, oa_buf, v_buf,
                                                      mid_buf);
  // out = mid @ W_out + b_out -> fp32
  gemm_out<<<dim3(mg, 2), blk, 0, stream>>>((const unsigned short*)mid_buf,
                                            Wout_t, b_out, out);
}

// Round 7
// 209.835 us; speedup vs baseline: 1.8010x; 1.0128x over previous
//
#include <hip/hip_runtime.h>
#include <math.h>

// ---- problem constants ----
#define BQ 2
#define LQ 13294
#define LEN_IN 13294
#define M_ROWS 26588          // BQ*LQ

__device__ __constant__ int c_HW[4]    = {100, 50, 25, 13};
__device__ __constant__ int c_START[4] = {0, 10000, 12500, 13125};

typedef __attribute__((ext_vector_type(8))) short bf16x8;
typedef __attribute__((ext_vector_type(4))) float f32x4;
typedef __attribute__((ext_vector_type(2))) float f32x2;

__device__ inline unsigned short f2bf(float f) {
  union { float f; unsigned int u; } x; x.f = f;
  unsigned int u = x.u;
  return (unsigned short)((u + 0x7fffu + ((u >> 16) & 1u)) >> 16);
}
__device__ inline float h2f(unsigned short h) {
  _Float16 x; __builtin_memcpy(&x, &h, 2); return (float)x;
}
__device__ inline unsigned short f2h(float f) {
  _Float16 x = (_Float16)f; unsigned short u; __builtin_memcpy(&u, &x, 2); return u;
}

__device__ inline void gl_lds16(const void* g, void* l) {
  __builtin_amdgcn_global_load_lds(
      (const __attribute__((address_space(1))) unsigned int*)g,
      (__attribute__((address_space(3))) unsigned int*)l, 16, 0, 0);
}

// ---------------------------------------------------------------------------
// Weight prep only (A conversion now happens inside the GEMMs): transpose +
// convert to bf16 [N][K] + fused oa bias. 896 blocks x 256 = exactly
// 65536 + 98304 + 65536 elements.
// ---------------------------------------------------------------------------
__global__ __launch_bounds__(256) void prep_w(
    const float* __restrict__ W_off, const float* __restrict__ b_off,
    const float* __restrict__ W_attn, const float* __restrict__ b_attn,
    const float* __restrict__ W_val, const float* __restrict__ W_out,
    unsigned short* __restrict__ Wval_t, unsigned short* __restrict__ Woa_t,
    unsigned short* __restrict__ Wout_t, float* __restrict__ b_oa) {
  const int idx = blockIdx.x * 256 + threadIdx.x;
  const int SZ1 = 256 * 256;
  const int SZ2 = 384 * 256;
  if (idx < SZ1) {
    const int n = idx >> 8, k = idx & 255;
    Wval_t[idx] = f2bf(W_val[k * 256 + n]);
  } else if (idx < SZ1 + SZ2) {
    const int j = idx - SZ1;
    const int n = j >> 8, k = j & 255;
    const float v = (n < 256) ? W_off[k * 256 + n] : W_attn[k * 128 + (n - 256)];
    Woa_t[j] = f2bf(v);
  } else {
    const int j = idx - SZ1 - SZ2;
    const int n = j >> 8, k = j & 255;
    Wout_t[j] = f2bf(W_out[k * 256 + n]);
  }
  if (blockIdx.x == 0) b_oa[threadIdx.x] = b_off[threadIdx.x];
  if (blockIdx.x == 1 && threadIdx.x < 128)
    b_oa[256 + threadIdx.x] = b_attn[threadIdx.x];
}

// ---------------------------------------------------------------------------
// Streaming GEMM, K=256: W slice (128x256 bf16, 64 KB) staged once in LDS
// (XOR-swizzled); A fragments preloaded to registers (fp32 variant converts
// in-register, removing the separate conversion pass); single barrier;
// operand-swapped mfma(b,a,acc) -> vectorized epilogue stores.
// CT: 0 = fp32 C, 1 = bf16 C, 2 = fp16 C.
// ---------------------------------------------------------------------------
__device__ inline void stage_W(const unsigned short* __restrict__ Wt,
                               int n0, int wv, int lane, unsigned short* Ws) {
#pragma unroll
  for (int it = 0; it < 16; ++it) {
    const int lin = wv * 1024 + it * 64 + lane;   // 16B-chunk linear index
    const int r = lin >> 5;                        // W row 0..127
    const int p = lin & 31;                        // physical chunk in row
    const int c = p ^ (r & 7);                     // logical chunk fetched
    gl_lds16(Wt + (size_t)(n0 + r) * 256 + c * 8,
             &Ws[(size_t)(wv * 1024 + it * 64) * 8]);
  }
}

template <int CT>
__device__ inline void kloop_epilogue(
    const bf16x8* a0f, const bf16x8* a1f, const unsigned short* Ws,
    const float* __restrict__ bias, void* __restrict__ Cp,
    int M, int N, int m0, int n0, int wv, int fr, int fq) {
  f32x4 acc[2][8];
#pragma unroll
  for (int mt = 0; mt < 2; ++mt)
#pragma unroll
    for (int n = 0; n < 8; ++n) acc[mt][n] = (f32x4){0.f, 0.f, 0.f, 0.f};

#pragma unroll
  for (int kk = 0; kk < 8; ++kk) {
#pragma unroll
    for (int n = 0; n < 8; ++n) {
      const int rn = n * 16 + fr;
      const bf16x8 b =
          *(const bf16x8*)&Ws[rn * 256 + (((kk * 4 + fq) ^ (rn & 7)) * 8)];
      acc[0][n] = __builtin_amdgcn_mfma_f32_16x16x32_bf16(b, a0f[kk], acc[0][n], 0, 0, 0);
      acc[1][n] = __builtin_amdgcn_mfma_f32_16x16x32_bf16(b, a1f[kk], acc[1][n], 0, 0, 0);
    }
  }

#pragma unroll
  for (int n = 0; n < 8; ++n) {
    const int nb = n0 + n * 16 + fq * 4;
    const float4 b4 = *(const float4*)&bias[nb];
#pragma unroll
    for (int mt = 0; mt < 2; ++mt) {
      const int m = m0 + wv * 32 + mt * 16 + fr;
      if (m >= M) continue;
      const float v0 = acc[mt][n][0] + b4.x;
      const float v1 = acc[mt][n][1] + b4.y;
      const float v2 = acc[mt][n][2] + b4.z;
      const float v3 = acc[mt][n][3] + b4.w;
      if (CT == 0) {
        *(float4*)&((float*)Cp)[(size_t)m * N + nb] = make_float4(v0, v1, v2, v3);
      } else if (CT == 1) {
        uint2 o;
        o.x = (unsigned int)f2bf(v0) | ((unsigned int)f2bf(v1) << 16);
        o.y = (unsigned int)f2bf(v2) | ((unsigned int)f2bf(v3) << 16);
        *(uint2*)&((unsigned short*)Cp)[(size_t)m * N + nb] = o;
      } else {
        uint2 o;
        o.x = (unsigned int)f2h(v0) | ((unsigned int)f2h(v1) << 16);
        o.y = (unsigned int)f2h(v2) | ((unsigned int)f2h(v3) << 16);
        *(uint2*)&((unsigned short*)Cp)[(size_t)m * N + nb] = o;
      }
    }
  }
}

// fp32-A variant: loads A as float4 pairs, converts to bf16 fragments in regs.
template <int CT>
__device__ inline void gemm_stream_f32A(
    const float* __restrict__ A, const unsigned short* __restrict__ Wt,
    const float* __restrict__ bias, void* __restrict__ Cp,
    int M, int N, int m0, int n0, unsigned short* Ws) {
  const int tid = threadIdx.x;
  const int wv = tid >> 6;
  const int lane = tid & 63;
  const int fr = lane & 15;
  const int fq = lane >> 4;

  int mr0 = m0 + wv * 32 + fr;       if (mr0 > M - 1) mr0 = M - 1;
  int mr1 = m0 + wv * 32 + 16 + fr;  if (mr1 > M - 1) mr1 = M - 1;
  const float* a0 = A + (size_t)mr0 * 256 + fq * 8;
  const float* a1 = A + (size_t)mr1 * 256 + fq * 8;

  bf16x8 a0f[8], a1f[8];
#pragma unroll
  for (int kk = 0; kk < 8; ++kk) {
    const float4 x0 = *(const float4*)(a0 + kk * 32);
    const float4 x1 = *(const float4*)(a0 + kk * 32 + 4);
    const float4 y0 = *(const float4*)(a1 + kk * 32);
    const float4 y1 = *(const float4*)(a1 + kk * 32 + 4);
    ushort4 h0, h1;
    h0.x = f2bf(x0.x); h0.y = f2bf(x0.y); h0.z = f2bf(x0.z); h0.w = f2bf(x0.w);
    h1.x = f2bf(x1.x); h1.y = f2bf(x1.y); h1.z = f2bf(x1.z); h1.w = f2bf(x1.w);
    union { ushort4 h[2]; bf16x8 v; } u0; u0.h[0] = h0; u0.h[1] = h1;
    a0f[kk] = u0.v;
    h0.x = f2bf(y0.x); h0.y = f2bf(y0.y); h0.z = f2bf(y0.z); h0.w = f2bf(y0.w);
    h1.x = f2bf(y1.x); h1.y = f2bf(y1.y); h1.z = f2bf(y1.z); h1.w = f2bf(y1.w);
    union { ushort4 h[2]; bf16x8 v; } u1; u1.h[0] = h0; u1.h[1] = h1;
    a1f[kk] = u1.v;
  }

  stage_W(Wt, n0, wv, lane, Ws);
  __syncthreads();   // the only barrier

  kloop_epilogue<CT>(a0f, a1f, Ws, bias, Cp, M, N, m0, n0, wv, fr, fq);
}

// bf16-A variant (for the out-projection; mid is already bf16).
template <int CT>
__device__ inline void gemm_stream_bf16A(
    const unsigned short* __restrict__ A, const unsigned short* __restrict__ Wt,
    const float* __restrict__ bias, void* __restrict__ Cp,
    int M, int N, int m0, int n0, unsigned short* Ws) {
  const int tid = threadIdx.x;
  const int wv = tid >> 6;
  const int lane = tid & 63;
  const int fr = lane & 15;
  const int fq = lane >> 4;

  int mr0 = m0 + wv * 32 + fr;       if (mr0 > M - 1) mr0 = M - 1;
  int mr1 = m0 + wv * 32 + 16 + fr;  if (mr1 > M - 1) mr1 = M - 1;
  const unsigned short* a0 = A + (size_t)mr0 * 256 + fq * 8;
  const unsigned short* a1 = A + (size_t)mr1 * 256 + fq * 8;
  bf16x8 a0f[8], a1f[8];
#pragma unroll
  for (int kk = 0; kk < 8; ++kk) {
    a0f[kk] = *(const bf16x8*)(a0 + kk * 32);
    a1f[kk] = *(const bf16x8*)(a1 + kk * 32);
  }

  stage_W(Wt, n0, wv, lane, Ws);
  __syncthreads();

  kloop_epilogue<CT>(a0f, a1f, Ws, bias, Cp, M, N, m0, n0, wv, fr, fq);
}

// value (y 0-1, A=input fp32, N=256, bf16 C) + oa (y 2-4, A=query fp32,
// N=384, fp16 C) fused.
__global__ __launch_bounds__(256) void gemm_vo(
    const float* __restrict__ inpf, const float* __restrict__ query,
    const unsigned short* __restrict__ Wval_t,
    const unsigned short* __restrict__ Woa_t,
    const float* __restrict__ b_val, const float* __restrict__ b_oa,
    void* __restrict__ v_buf, void* __restrict__ oa_buf) {
  __shared__ unsigned short Ws[128 * 256];
  const int m0 = blockIdx.x * 128;
  if (blockIdx.y < 2) {
    gemm_stream_f32A<1>(inpf, Wval_t, b_val, v_buf, M_ROWS, 256,
                        m0, blockIdx.y * 128, Ws);
  } else {
    gemm_stream_f32A<2>(query, Woa_t, b_oa, oa_buf, M_ROWS, 384,
                        m0, (blockIdx.y - 2) * 128, Ws);
  }
}

__global__ __launch_bounds__(256) void gemm_out(
    const unsigned short* __restrict__ mid,
    const unsigned short* __restrict__ Wout_t,
    const float* __restrict__ b_out, float* __restrict__ out) {
  __shared__ unsigned short Ws[128 * 256];
  gemm_stream_bf16A<0>(mid, Wout_t, b_out, out, M_ROWS, 256,
                       blockIdx.x * 128, blockIdx.y * 128, Ws);
}

// ---------------------------------------------------------------------------
// Sampler (R4-proven structure): 2 queries/block, 256 threads.
// Phase A: per-point softmax (16-lane shuffles) + tap {weight, byteoff} -> LDS
//   (float2, [tap][h*17+lp] layout -- zero bank conflicts measured).
// Phase B: 128 thr/query, thread owns (head, d-pair): 64 taps, each one
//   ds_read_b64 + one u32 (2 bf16) global load + packed f32x2 FMA.
// ---------------------------------------------------------------------------
__global__ __launch_bounds__(256) void sample_kernel(
    const float* __restrict__ refp,           // (B,LQ,4,2) fp32
    const unsigned short* __restrict__ oa,    // (M,384) fp16: off|logits
    const unsigned short* __restrict__ value, // (M,256) bf16
    unsigned int* __restrict__ mid) {         // (M,128) u32 bf16-pairs
  const int tid = threadIdx.x;
  const int qi = tid >> 7;
  const int q = blockIdx.x * 2 + qi;
  const int b = (q >= LQ) ? 1 : 0;

  __shared__ float2 s_wo[2][4][136];          // [qi][tap][h*17+lp]

  // ---- Phase A ----
  {
    const int pid = tid & 127;                // h*16 + l*4 + p
    const int h = pid >> 4;
    const int lp = pid & 15;
    const int l = lp >> 2;
    const int p = lp & 3;
    const int HW = c_HW[l];
    const float fW = (float)HW;

    const float logit = h2f(oa[(size_t)q * 384 + 256 + pid]);
    float mx = logit;
#pragma unroll
    for (int s = 1; s < 16; s <<= 1) mx = fmaxf(mx, __shfl_xor(mx, s, 16));
    const float e = expf(logit - mx);
    float sum = e;
#pragma unroll
    for (int s = 1; s < 16; s <<= 1) sum += __shfl_xor(sum, s, 16);
    const float a = e / sum;

    const unsigned int opk =
        *(const unsigned int*)&oa[(size_t)q * 384 + h * 32 + l * 8 + p * 2];
    const float ox = h2f((unsigned short)(opk & 0xffffu));
    const float oy = h2f((unsigned short)(opk >> 16));
    const float rx = refp[((size_t)q * 4 + l) * 2 + 0];
    const float ry = refp[((size_t)q * 4 + l) * 2 + 1];
    // (rx + ox/W)*W - 0.5 == rx*W + ox - 0.5
    const float x = fmaf(rx, fW, ox - 0.5f);
    const float y = fmaf(ry, fW, oy - 0.5f);
    const float x0 = floorf(x);
    const float y0 = floorf(y);

#pragma unroll
    for (int t = 0; t < 4; ++t) {
      const int dx = t & 1;
      const int dy = t >> 1;
      const float xi = x0 + (float)dx;
      const float yi = y0 + (float)dy;
      const float wgt = (1.0f - fabsf(x - xi)) * (1.0f - fabsf(y - yi));
      const bool valid =
          (xi >= 0.f) && (xi <= fW - 1.f) && (yi >= 0.f) && (yi <= fW - 1.f);
      int xc = (int)xi; xc = xc < 0 ? 0 : (xc > HW - 1 ? HW - 1 : xc);
      int yc = (int)yi; yc = yc < 0 ? 0 : (yc > HW - 1 ? HW - 1 : yc);
      const int row = b * LEN_IN + c_START[l] + yc * HW + xc;
      float2 wo;
      wo.x = valid ? wgt * a : 0.f;
      wo.y = __int_as_float(row * 512 + h * 64);  // bf16 row = 512 B
      s_wo[qi][t][h * 17 + lp] = wo;
    }
  }
  __syncthreads();

  // ---- Phase B ----
  {
    const int g = tid & 127;
    const int h = g >> 4;
    const int dp = g & 15;                    // d-pair
    const char* vbase = (const char*)value + dp * 4;
    f32x2 acc = {0.f, 0.f};
#pragma unroll 4
    for (int lp = 0; lp < 16; ++lp) {
      const int si = h * 17 + lp;
#pragma unroll
      for (int t = 0; t < 4; ++t) {
        const float2 f = s_wo[qi][t][si];
        const unsigned int v = *(const unsigned int*)(vbase + __float_as_int(f.y));
        f32x2 av = {__uint_as_float(v << 16), __uint_as_float(v & 0xffff0000u)};
        acc += f.x * av;
      }
    }
    mid[(size_t)q * 128 + h * 16 + dp] =
        (unsigned int)f2bf(acc.x) | ((unsigned int)f2bf(acc.y) << 16);
  }
}

// ---------------------------------------------------------------------------
extern "C" void kernel_launch(void* const* d_in, const int* in_sizes, int n_in,
                              void* d_out, int out_size, void* d_ws,
                              size_t ws_size, hipStream_t stream) {
  const float* query  = (const float*)d_in[0];
  const float* refp   = (const float*)d_in[1];
  const float* inpf   = (const float*)d_in[2];
  const float* W_off  = (const float*)d_in[5];
  const float* b_off  = (const float*)d_in[6];
  const float* W_attn = (const float*)d_in[7];
  const float* b_attn = (const float*)d_in[8];
  const float* W_val  = (const float*)d_in[9];
  const float* b_val  = (const float*)d_in[10];
  const float* W_out  = (const float*)d_in[11];
  const float* b_out  = (const float*)d_in[12];
  float* out = (float*)d_out;

  unsigned char* w = (unsigned char*)d_ws;
  unsigned short* Wval_t = (unsigned short*)w;  w += 256 * 256 * 2;
  unsigned short* Woa_t  = (unsigned short*)w;  w += 384 * 256 * 2;
  unsigned short* Wout_t = (unsigned short*)w;  w += 256 * 256 * 2;
  float*          b_oa   = (float*)w;           w += 384 * 4 + 64;
  unsigned short* v_buf  = (unsigned short*)w;  w += (size_t)M_ROWS * 256 * 2;
  unsigned short* oa_buf = (unsigned short*)w;  w += (size_t)M_ROWS * 384 * 2;
  unsigned int*   mid_buf = (unsigned int*)w;   // M*128 u32

  const dim3 blk(256);
  const int mg = (M_ROWS + 127) / 128;   // 208

  // weights only (A conversion is fused into gemm_vo)
  prep_w<<<dim3(896), blk, 0, stream>>>(W_off, b_off, W_attn, b_attn,
                                        W_val, W_out, Wval_t, Woa_t,
                                        Wout_t, b_oa);
  // value -> bf16 ; off|logits -> fp16 (fp32 A, in-register conversion)
  gemm_vo<<<dim3(mg, 5), blk, 0, stream>>>(inpf, query, Wval_t, Woa_t,
                                           b_val, b_oa, v_buf, oa_buf);
  // softmax + bilinear sampling -> mid (bf16 pairs)
  sample_kernel<<<dim3(M_ROWS / 2), blk, 0, stream>>>(refp, oa_buf, v_buf,
                                                      mid_buf);
  // out = mid @ W_out + b_out -> fp32
  gemm_out<<<dim3(mg, 2), blk, 0, stream>>>((const unsigned short*)mid_buf,
                                            Wout_t, b_out, out);
}